// Round 1
// baseline (1557.056 us; speedup 1.0000x reference)
//
#include <hip/hip_runtime.h>
#include <hip/hip_bf16.h>

#define N_NODES 50000
#define E_EDGES 800000
#define IN_F 256
#define H_F 128
#define OUT_F 64
#define L_LAYERS 3

// ---------------- degree histogram ----------------
__global__ void deg_kernel(const int* __restrict__ dst, float* __restrict__ deg) {
    int e = blockIdx.x * blockDim.x + threadIdx.x;
    if (e < E_EDGES) atomicAdd(&deg[dst[e]], 1.0f);
}

// ---------------- lin0: h = relu(x @ W + b), x[N,256] W[256,128] ----------------
// block = 128 threads (one per output col), 8 rows per block
__global__ void lin0_kernel(const float* __restrict__ x, const float* __restrict__ w,
                            const float* __restrict__ b, float* __restrict__ h) {
    __shared__ float xs[8][IN_F];
    const int row0 = blockIdx.x * 8;
    const int col = threadIdx.x;
    for (int i = threadIdx.x; i < 8 * IN_F; i += 128) {
        int r = i >> 8;          // /256
        int k = i & (IN_F - 1);  // %256
        xs[r][k] = x[(row0 + r) * IN_F + k];
    }
    __syncthreads();
    float acc[8] = {};
    for (int k = 0; k < IN_F; ++k) {
        float wv = w[k * H_F + col];
#pragma unroll
        for (int r = 0; r < 8; ++r) acc[r] += xs[r][k] * wv;
    }
    float bv = b[col];
#pragma unroll
    for (int r = 0; r < 8; ++r)
        h[(row0 + r) * H_F + col] = fmaxf(acc[r] + bv, 0.0f);
}

// ---------------- scatter: agg[dst] += h[src], flattened (edge,feature) ----------------
__global__ void scatter_kernel(const int* __restrict__ ei, const float* __restrict__ h,
                               float* __restrict__ agg) {
    const long long total = (long long)E_EDGES * H_F;
    long long stride = (long long)gridDim.x * blockDim.x;
    for (long long i = (long long)blockIdx.x * blockDim.x + threadIdx.x; i < total; i += stride) {
        int f = (int)(i & (H_F - 1));
        int e = (int)(i >> 7);
        int s = ei[e];
        int d = ei[E_EDGES + e];
        atomicAdd(&agg[d * H_F + f], h[s * H_F + f]);
    }
}

// ---------------- fused SAGEConv: out = relu((agg/deg)@wl + h@wr + bl), in-place into agg ----------------
// block = 128 threads (one per col), 8 rows per block
__global__ void conv_kernel(const float* __restrict__ h, float* __restrict__ agg,
                            const float* __restrict__ wl, const float* __restrict__ bl,
                            const float* __restrict__ wr, const float* __restrict__ deg) {
    __shared__ float hs[8][H_F];
    __shared__ float as[8][H_F];
    const int row0 = blockIdx.x * 8;
    const int col = threadIdx.x;
#pragma unroll
    for (int r = 0; r < 8; ++r) {
        int row = row0 + r;
        float d = fmaxf(deg[row], 1.0f);
        hs[r][col] = h[row * H_F + col];
        as[r][col] = agg[row * H_F + col] / d;
    }
    __syncthreads();
    float acc[8] = {};
    for (int k = 0; k < H_F; ++k) {
        float wlv = wl[k * H_F + col];
        float wrv = wr[k * H_F + col];
#pragma unroll
        for (int r = 0; r < 8; ++r) acc[r] += as[r][k] * wlv + hs[r][k] * wrv;
    }
    float bv = bl[col];
#pragma unroll
    for (int r = 0; r < 8; ++r)
        agg[(row0 + r) * H_F + col] = fmaxf(acc[r] + bv, 0.0f);  // safe: rows already in LDS
}

// ---------------- lin1: out = h @ W + b, [N,128]x[128,64] ----------------
// block = 64 threads (one per col), 8 rows per block
__global__ void lin1_kernel(const float* __restrict__ h, const float* __restrict__ w,
                            const float* __restrict__ b, float* __restrict__ out) {
    __shared__ float hs[8][H_F];
    const int row0 = blockIdx.x * 8;
    const int t = threadIdx.x;
    for (int i = t; i < 8 * H_F; i += 64) {
        int r = i >> 7;
        int k = i & (H_F - 1);
        hs[r][k] = h[(row0 + r) * H_F + k];
    }
    __syncthreads();
    float acc[8] = {};
    for (int k = 0; k < H_F; ++k) {
        float wv = w[k * OUT_F + t];
#pragma unroll
        for (int r = 0; r < 8; ++r) acc[r] += hs[r][k] * wv;
    }
    float bv = b[t];
#pragma unroll
    for (int r = 0; r < 8; ++r)
        out[(row0 + r) * OUT_F + t] = acc[r] + bv;
}

extern "C" void kernel_launch(void* const* d_in, const int* in_sizes, int n_in,
                              void* d_out, int out_size, void* d_ws, size_t ws_size,
                              hipStream_t stream) {
    const float* x       = (const float*)d_in[0];
    const int*   ei      = (const int*)d_in[1];   // [2,E]: row0=src, row1=dst
    const float* lin0_w  = (const float*)d_in[2];
    const float* lin0_b  = (const float*)d_in[3];
    const float* conv_wl = (const float*)d_in[4]; // [L,H,H]
    const float* conv_bl = (const float*)d_in[5]; // [L,H]
    const float* conv_wr = (const float*)d_in[6]; // [L,H,H]
    const float* lin1_w  = (const float*)d_in[7];
    const float* lin1_b  = (const float*)d_in[8];
    float* out = (float*)d_out;

    char* ws = (char*)d_ws;
    float* deg  = (float*)ws;                          // N floats
    size_t off = ((size_t)N_NODES * 4 + 255) & ~(size_t)255;
    float* bufA = (float*)(ws + off);                  // N*H floats
    float* bufB = bufA + (size_t)N_NODES * H_F;        // N*H floats

    // degree (ws is poisoned 0xAA every call -> must zero)
    hipMemsetAsync(deg, 0, (size_t)N_NODES * 4, stream);
    deg_kernel<<<(E_EDGES + 255) / 256, 256, 0, stream>>>(ei + E_EDGES, deg);

    // lin0
    lin0_kernel<<<N_NODES / 8, 128, 0, stream>>>(x, lin0_w, lin0_b, bufA);

    float* h = bufA;
    float* agg = bufB;
    for (int l = 0; l < L_LAYERS; ++l) {
        hipMemsetAsync(agg, 0, (size_t)N_NODES * H_F * 4, stream);
        scatter_kernel<<<2048, 256, 0, stream>>>(ei, h, agg);
        conv_kernel<<<N_NODES / 8, 128, 0, stream>>>(h, agg,
                                                     conv_wl + (size_t)l * H_F * H_F,
                                                     conv_bl + (size_t)l * H_F,
                                                     conv_wr + (size_t)l * H_F * H_F,
                                                     deg);
        float* tmp = h; h = agg; agg = tmp;  // conv wrote new h into agg buffer
    }

    // lin1 -> d_out
    lin1_kernel<<<N_NODES / 8, 64, 0, stream>>>(h, lin1_w, lin1_b, out);
}

// Round 2
// 803.235 us; speedup vs baseline: 1.9385x; 1.9385x over previous
//
#include <hip/hip_runtime.h>
#include <hip/hip_bf16.h>

#define N_NODES 50000
#define E_EDGES 800000
#define IN_F 256
#define H_F 128
#define OUT_F 64
#define L_LAYERS 3

// ================= CSR build =================

// count degrees into cursor (int)
__global__ void count_kernel(const int* __restrict__ dst, int* __restrict__ cursor) {
    int e = blockIdx.x * blockDim.x + threadIdx.x;
    if (e < E_EDGES) atomicAdd(&cursor[dst[e]], 1);
}

// single-block exclusive scan: row_ptr[i] = sum cnt[0..i-1], row_ptr[N] = E
__global__ void scan_kernel(const int* __restrict__ cnt, int* __restrict__ row_ptr) {
    __shared__ int buf[1024];
    __shared__ int carry;
    const int tid = threadIdx.x;
    if (tid == 0) carry = 0;
    __syncthreads();
    for (int base = 0; base < N_NODES; base += 1024) {
        int i = base + tid;
        int v = (i < N_NODES) ? cnt[i] : 0;
        buf[tid] = v;
        __syncthreads();
        for (int off = 1; off < 1024; off <<= 1) {
            int t = (tid >= off) ? buf[tid - off] : 0;
            __syncthreads();
            buf[tid] += t;
            __syncthreads();
        }
        int incl = buf[tid];
        int c = carry;
        if (i < N_NODES) row_ptr[i] = c + incl - v;
        __syncthreads();
        if (tid == 0) carry += buf[1023];
        __syncthreads();
    }
    if (tid == 0) row_ptr[N_NODES] = carry;
}

// place src ids into CSR slots: esrc[cursor[dst]++] = src
__global__ void place_kernel(const int* __restrict__ ei, int* __restrict__ cursor,
                             int* __restrict__ esrc) {
    int e = blockIdx.x * blockDim.x + threadIdx.x;
    if (e < E_EDGES) {
        int s = ei[e];
        int d = ei[E_EDGES + e];
        int pos = atomicAdd(&cursor[d], 1);
        esrc[pos] = s;
    }
}

// ================= lin0: h = relu(x @ W + b) =================
__global__ void lin0_kernel(const float* __restrict__ x, const float* __restrict__ w,
                            const float* __restrict__ b, float* __restrict__ h) {
    __shared__ float xs[8][IN_F];
    const int row0 = blockIdx.x * 8;
    const int col = threadIdx.x;
    for (int i = threadIdx.x; i < 8 * IN_F; i += 128) {
        int r = i >> 8;
        int k = i & (IN_F - 1);
        xs[r][k] = x[(row0 + r) * IN_F + k];
    }
    __syncthreads();
    float acc[8] = {};
    for (int k = 0; k < IN_F; ++k) {
        float wv = w[k * H_F + col];
#pragma unroll
        for (int r = 0; r < 8; ++r) acc[r] += xs[r][k] * wv;
    }
    float bv = b[col];
#pragma unroll
    for (int r = 0; r < 8; ++r)
        h[(row0 + r) * H_F + col] = fmaxf(acc[r] + bv, 0.0f);
}

// ================= fused SAGEConv =================
// block = 512 threads (8 waves), 8 nodes/block, one wave per node for aggregation.
// out = relu((mean_agg)@wl + h@wr + bl)
__global__ __launch_bounds__(512) void fused_conv_kernel(
        const float* __restrict__ h, float* __restrict__ out,
        const int* __restrict__ row_ptr, const int* __restrict__ esrc,
        const float* __restrict__ wl, const float* __restrict__ bl,
        const float* __restrict__ wr) {
    __shared__ float as[8][H_F];
    __shared__ float hs[8][H_F];
    const int row0 = blockIdx.x * 8;
    const int tid = threadIdx.x;
    const int wave = tid >> 6;   // 0..7 -> node
    const int lane = tid & 63;   // float2 slot

    // ---- aggregation: wave `wave` owns node row0+wave ----
    {
        const int node = row0 + wave;
        const int s0 = row_ptr[node];
        const int s1 = row_ptr[node + 1];
        const float2* h2 = (const float2*)h;
        float2 acc = make_float2(0.0f, 0.0f);
        int j = s0;
        for (; j + 1 < s1; j += 2) {
            int sa = esrc[j];
            int sb = esrc[j + 1];
            float2 va = h2[(size_t)sa * 64 + lane];
            float2 vb = h2[(size_t)sb * 64 + lane];
            acc.x += va.x + vb.x;
            acc.y += va.y + vb.y;
        }
        if (j < s1) {
            int sa = esrc[j];
            float2 va = h2[(size_t)sa * 64 + lane];
            acc.x += va.x;
            acc.y += va.y;
        }
        float dinv = 1.0f / (float)max(s1 - s0, 1);
        float2 hv = h2[(size_t)node * 64 + lane];
        ((float2*)&as[wave][0])[lane] = make_float2(acc.x * dinv, acc.y * dinv);
        ((float2*)&hs[wave][0])[lane] = hv;
    }
    __syncthreads();

    // ---- dual GEMM: 8 rows x 128 cols over 512 threads -> 2 outputs/thread ----
    const int col = tid & (H_F - 1);
    const int g = tid >> 7;  // 0..3, handles rows g and g+4
    float acc0 = 0.0f, acc1 = 0.0f;
    for (int k = 0; k < H_F; ++k) {
        float wlv = wl[k * H_F + col];
        float wrv = wr[k * H_F + col];
        acc0 += as[g][k] * wlv + hs[g][k] * wrv;
        acc1 += as[g + 4][k] * wlv + hs[g + 4][k] * wrv;
    }
    float bv = bl[col];
    out[(size_t)(row0 + g) * H_F + col]     = fmaxf(acc0 + bv, 0.0f);
    out[(size_t)(row0 + g + 4) * H_F + col] = fmaxf(acc1 + bv, 0.0f);
}

// ================= lin1: out = h @ W + b =================
__global__ void lin1_kernel(const float* __restrict__ h, const float* __restrict__ w,
                            const float* __restrict__ b, float* __restrict__ out) {
    __shared__ float hs[8][H_F];
    const int row0 = blockIdx.x * 8;
    const int t = threadIdx.x;
    for (int i = t; i < 8 * H_F; i += 64) {
        int r = i >> 7;
        int k = i & (H_F - 1);
        hs[r][k] = h[(row0 + r) * H_F + k];
    }
    __syncthreads();
    float acc[8] = {};
    for (int k = 0; k < H_F; ++k) {
        float wv = w[k * OUT_F + t];
#pragma unroll
        for (int r = 0; r < 8; ++r) acc[r] += hs[r][k] * wv;
    }
    float bv = b[t];
#pragma unroll
    for (int r = 0; r < 8; ++r)
        out[(row0 + r) * OUT_F + t] = acc[r] + bv;
}

extern "C" void kernel_launch(void* const* d_in, const int* in_sizes, int n_in,
                              void* d_out, int out_size, void* d_ws, size_t ws_size,
                              hipStream_t stream) {
    const float* x       = (const float*)d_in[0];
    const int*   ei      = (const int*)d_in[1];   // [2,E]: row0=src, row1=dst
    const float* lin0_w  = (const float*)d_in[2];
    const float* lin0_b  = (const float*)d_in[3];
    const float* conv_wl = (const float*)d_in[4];
    const float* conv_bl = (const float*)d_in[5];
    const float* conv_wr = (const float*)d_in[6];
    const float* lin1_w  = (const float*)d_in[7];
    const float* lin1_b  = (const float*)d_in[8];
    float* out = (float*)d_out;

    char* ws = (char*)d_ws;
    size_t off = 0;
    auto alloc = [&](size_t bytes) {
        void* p = ws + off;
        off = (off + bytes + 255) & ~(size_t)255;
        return p;
    };
    int*   cursor  = (int*)alloc((size_t)N_NODES * 4);
    int*   row_ptr = (int*)alloc((size_t)(N_NODES + 1) * 4);
    int*   esrc    = (int*)alloc((size_t)E_EDGES * 4);
    float* bufA    = (float*)alloc((size_t)N_NODES * H_F * 4);
    float* bufB    = (float*)alloc((size_t)N_NODES * H_F * 4);

    // ---- CSR build (once per call; ws is re-poisoned each call) ----
    hipMemsetAsync(cursor, 0, (size_t)N_NODES * 4, stream);
    count_kernel<<<(E_EDGES + 255) / 256, 256, 0, stream>>>(ei + E_EDGES, cursor);
    scan_kernel<<<1, 1024, 0, stream>>>(cursor, row_ptr);
    hipMemcpyAsync(cursor, row_ptr, (size_t)N_NODES * 4, hipMemcpyDeviceToDevice, stream);
    place_kernel<<<(E_EDGES + 255) / 256, 256, 0, stream>>>(ei, cursor, esrc);

    // ---- lin0 ----
    lin0_kernel<<<N_NODES / 8, 128, 0, stream>>>(x, lin0_w, lin0_b, bufA);

    // ---- 3 fused SAGEConv layers ----
    float* h = bufA;
    float* nh = bufB;
    for (int l = 0; l < L_LAYERS; ++l) {
        fused_conv_kernel<<<N_NODES / 8, 512, 0, stream>>>(
            h, nh, row_ptr, esrc,
            conv_wl + (size_t)l * H_F * H_F,
            conv_bl + (size_t)l * H_F,
            conv_wr + (size_t)l * H_F * H_F);
        float* tmp = h; h = nh; nh = tmp;
    }

    // ---- lin1 -> d_out ----
    lin1_kernel<<<N_NODES / 8, 64, 0, stream>>>(h, lin1_w, lin1_b, out);
}

// Round 3
// 641.130 us; speedup vs baseline: 2.4286x; 1.2528x over previous
//
#include <hip/hip_runtime.h>
#include <hip/hip_bf16.h>

#define N_NODES 50000
#define E_EDGES 800000
#define IN_F 256
#define H_F 128
#define OUT_F 64
#define L_LAYERS 3
#define NB_SCAN 49   // ceil(50000/1024)

static __device__ __forceinline__ float bf2f(unsigned short u) {
    return __uint_as_float(((unsigned int)u) << 16);
}
static __device__ __forceinline__ unsigned short f2bf(float f) {
    unsigned int b = __float_as_uint(f);
    return (unsigned short)((b + 0x7FFFu + ((b >> 16) & 1u)) >> 16);  // RTN-even
}

// ================= CSR build =================
__global__ void count_kernel(const int* __restrict__ dst, int* __restrict__ cnt) {
    int e = blockIdx.x * blockDim.x + threadIdx.x;
    if (e < E_EDGES) atomicAdd(&cnt[dst[e]], 1);
}

// per-chunk inclusive scan (1024 elems/block)
__global__ __launch_bounds__(1024) void scanA_kernel(const int* __restrict__ cnt,
                                                     int* __restrict__ tmp,
                                                     int* __restrict__ bsum) {
    __shared__ int buf[1024];
    const int tid = threadIdx.x;
    const int i = blockIdx.x * 1024 + tid;
    int v = (i < N_NODES) ? cnt[i] : 0;
    buf[tid] = v;
    __syncthreads();
    for (int off = 1; off < 1024; off <<= 1) {
        int t = (tid >= off) ? buf[tid - off] : 0;
        __syncthreads();
        buf[tid] += t;
        __syncthreads();
    }
    tmp[i] = buf[tid];
    if (tid == 1023) bsum[blockIdx.x] = buf[1023];
}

// exclusive scan of NB_SCAN block sums (single wave)
__global__ void scanB_kernel(int* __restrict__ bsum) {
    int t = threadIdx.x;  // 64
    int v = (t < NB_SCAN) ? bsum[t] : 0;
    int incl = v;
    for (int off = 1; off < 64; off <<= 1) {
        int u = __shfl_up(incl, off, 64);
        if (t >= off) incl += u;
    }
    if (t < NB_SCAN) bsum[t] = incl - v;  // exclusive
}

// row_ptr[i+1] = incl[i]+boff ; cursor[i] = exclusive start
__global__ __launch_bounds__(1024) void scanC_kernel(const int* __restrict__ tmp,
                                                     const int* __restrict__ bsum,
                                                     int* __restrict__ cursor,  // holds cnt on entry
                                                     int* __restrict__ row_ptr) {
    const int i = blockIdx.x * 1024 + threadIdx.x;
    if (i < N_NODES) {
        int incl = tmp[i] + bsum[i >> 10];
        row_ptr[i + 1] = incl;
        cursor[i] = incl - cursor[i];  // exclusive start (cursor held cnt)
    }
    if (i == 0) row_ptr[0] = 0;
}

__global__ void place_kernel(const int* __restrict__ ei, int* __restrict__ cursor,
                             int* __restrict__ esrc) {
    int e = blockIdx.x * blockDim.x + threadIdx.x;
    if (e < E_EDGES) {
        int s = ei[e];
        int d = ei[E_EDGES + e];
        int pos = atomicAdd(&cursor[d], 1);
        esrc[pos] = s;
    }
}

// ================= aggregation: G[n] = mean_{src in N(n)} hb[src] =================
// 1 wave per node; lane parity p handles edges j+p, j+p+2; feature quad q = (lane&31)*4
__global__ __launch_bounds__(256, 8) void agg_kernel(
        const unsigned short* __restrict__ hb, const int* __restrict__ row_ptr,
        const int* __restrict__ esrc, float* __restrict__ G) {
    const int wid = (blockIdx.x * 256 + threadIdx.x) >> 6;  // node
    const int lane = threadIdx.x & 63;
    const int p = lane >> 5;
    const int q = lane & 31;
    const int s0 = row_ptr[wid];
    const int s1 = row_ptr[wid + 1];
    float a0 = 0.f, a1 = 0.f, a2 = 0.f, a3 = 0.f;
    int j = s0;
    for (; j + 4 <= s1; j += 4) {
        int sa = esrc[j + p];
        int sb = esrc[j + p + 2];
        ushort4 va = *(const ushort4*)(hb + ((size_t)sa << 7) + (q << 2));
        ushort4 vb = *(const ushort4*)(hb + ((size_t)sb << 7) + (q << 2));
        a0 += bf2f(va.x) + bf2f(vb.x);
        a1 += bf2f(va.y) + bf2f(vb.y);
        a2 += bf2f(va.z) + bf2f(vb.z);
        a3 += bf2f(va.w) + bf2f(vb.w);
    }
    if (j + p < s1) {
        ushort4 v = *(const ushort4*)(hb + ((size_t)esrc[j + p] << 7) + (q << 2));
        a0 += bf2f(v.x); a1 += bf2f(v.y); a2 += bf2f(v.z); a3 += bf2f(v.w);
    }
    if (j + p + 2 < s1) {
        ushort4 v = *(const ushort4*)(hb + ((size_t)esrc[j + p + 2] << 7) + (q << 2));
        a0 += bf2f(v.x); a1 += bf2f(v.y); a2 += bf2f(v.z); a3 += bf2f(v.w);
    }
    // combine parities (both halves end with the full sum)
    a0 += __shfl(a0, lane ^ 32);
    a1 += __shfl(a1, lane ^ 32);
    a2 += __shfl(a2, lane ^ 32);
    a3 += __shfl(a3, lane ^ 32);
    if (p == 0) {
        float dinv = 1.0f / (float)max(s1 - s0, 1);
        float4 o = make_float4(a0 * dinv, a1 * dinv, a2 * dinv, a3 * dinv);
        *(float4*)(G + ((size_t)wid << 7) + (q << 2)) = o;
    }
}

// ================= lin0: h = relu(x @ W + b), writes fp32 + bf16 =================
// 512 thr, 64 rows x 128 cols, thread 4x4
__global__ __launch_bounds__(512, 4) void lin0_gemm(
        const float* __restrict__ x, const float* __restrict__ w,
        const float* __restrict__ b, float* __restrict__ h,
        unsigned short* __restrict__ hb) {
    __shared__ float xs[64][IN_F];
    const int tid = threadIdx.x;
    const int row0 = blockIdx.x * 64;
    for (int i = tid; i < 64 * (IN_F / 4); i += 512) {
        int r = i >> 6;
        int c4 = i & 63;
        int row = min(row0 + r, N_NODES - 1);
        *(float4*)(&xs[r][c4 * 4]) = *(const float4*)(x + (size_t)row * IN_F + c4 * 4);
    }
    __syncthreads();
    const int tx = tid & 31, c0 = tx * 4;
    const int ty = tid >> 5, r0 = ty * 4;
    float acc[4][4] = {};
    for (int k = 0; k < IN_F; k += 4) {
        float4 wv[4];
#pragma unroll
        for (int kk = 0; kk < 4; ++kk)
            wv[kk] = *(const float4*)(w + (size_t)(k + kk) * H_F + c0);
#pragma unroll
        for (int i = 0; i < 4; ++i) {
            float4 av = *(const float4*)(&xs[r0 + i][k]);
            const float* ap = (const float*)&av;
#pragma unroll
            for (int kk = 0; kk < 4; ++kk) {
                acc[i][0] += ap[kk] * wv[kk].x;
                acc[i][1] += ap[kk] * wv[kk].y;
                acc[i][2] += ap[kk] * wv[kk].z;
                acc[i][3] += ap[kk] * wv[kk].w;
            }
        }
    }
    float4 bv = *(const float4*)(b + c0);
#pragma unroll
    for (int i = 0; i < 4; ++i) {
        int row = min(row0 + r0 + i, N_NODES - 1);
        float o0 = fmaxf(acc[i][0] + bv.x, 0.f);
        float o1 = fmaxf(acc[i][1] + bv.y, 0.f);
        float o2 = fmaxf(acc[i][2] + bv.z, 0.f);
        float o3 = fmaxf(acc[i][3] + bv.w, 0.f);
        *(float4*)(h + (size_t)row * H_F + c0) = make_float4(o0, o1, o2, o3);
        ushort4 ob = {f2bf(o0), f2bf(o1), f2bf(o2), f2bf(o3)};
        *(ushort4*)(hb + (size_t)row * H_F + c0) = ob;
    }
}

// ================= conv GEMM: out = relu(G@wl + h@wr + bl), in-place into G =================
__global__ __launch_bounds__(512, 4) void conv_gemm(
        float* __restrict__ G, const float* __restrict__ h,
        const float* __restrict__ wl, const float* __restrict__ wr,
        const float* __restrict__ bl, unsigned short* __restrict__ hbout) {
    __shared__ float As[64][H_F];
    __shared__ float Hs[64][H_F];
    const int tid = threadIdx.x;
    const int row0 = blockIdx.x * 64;
    for (int i = tid; i < 64 * (H_F / 4); i += 512) {
        int r = i >> 5;
        int c4 = i & 31;
        int row = min(row0 + r, N_NODES - 1);
        *(float4*)(&As[r][c4 * 4]) = *(const float4*)(G + (size_t)row * H_F + c4 * 4);
        *(float4*)(&Hs[r][c4 * 4]) = *(const float4*)(h + (size_t)row * H_F + c4 * 4);
    }
    __syncthreads();
    const int tx = tid & 31, c0 = tx * 4;
    const int ty = tid >> 5, r0 = ty * 4;
    float acc[4][4] = {};
    for (int k = 0; k < H_F; k += 4) {
        float4 wlv[4], wrv[4];
#pragma unroll
        for (int kk = 0; kk < 4; ++kk) {
            wlv[kk] = *(const float4*)(wl + (size_t)(k + kk) * H_F + c0);
            wrv[kk] = *(const float4*)(wr + (size_t)(k + kk) * H_F + c0);
        }
#pragma unroll
        for (int i = 0; i < 4; ++i) {
            float4 av = *(const float4*)(&As[r0 + i][k]);
            float4 hv = *(const float4*)(&Hs[r0 + i][k]);
            const float* ap = (const float*)&av;
            const float* hp = (const float*)&hv;
#pragma unroll
            for (int kk = 0; kk < 4; ++kk) {
                acc[i][0] += ap[kk] * wlv[kk].x + hp[kk] * wrv[kk].x;
                acc[i][1] += ap[kk] * wlv[kk].y + hp[kk] * wrv[kk].y;
                acc[i][2] += ap[kk] * wlv[kk].z + hp[kk] * wrv[kk].z;
                acc[i][3] += ap[kk] * wlv[kk].w + hp[kk] * wrv[kk].w;
            }
        }
    }
    float4 bv = *(const float4*)(bl + c0);
#pragma unroll
    for (int i = 0; i < 4; ++i) {
        int row = min(row0 + r0 + i, N_NODES - 1);
        float o0 = fmaxf(acc[i][0] + bv.x, 0.f);
        float o1 = fmaxf(acc[i][1] + bv.y, 0.f);
        float o2 = fmaxf(acc[i][2] + bv.z, 0.f);
        float o3 = fmaxf(acc[i][3] + bv.w, 0.f);
        *(float4*)(G + (size_t)row * H_F + c0) = make_float4(o0, o1, o2, o3);
        ushort4 ob = {f2bf(o0), f2bf(o1), f2bf(o2), f2bf(o3)};
        *(ushort4*)(hbout + (size_t)row * H_F + c0) = ob;
    }
}

// ================= lin1: out = h @ W + b =================
// 256 thr, 64 rows x 64 cols, thread 4x4
__global__ __launch_bounds__(256, 4) void lin1_gemm(
        const float* __restrict__ h, const float* __restrict__ w,
        const float* __restrict__ b, float* __restrict__ out) {
    __shared__ float hs[64][H_F];
    const int tid = threadIdx.x;
    const int row0 = blockIdx.x * 64;
    for (int i = tid; i < 64 * (H_F / 4); i += 256) {
        int r = i >> 5;
        int c4 = i & 31;
        int row = min(row0 + r, N_NODES - 1);
        *(float4*)(&hs[r][c4 * 4]) = *(const float4*)(h + (size_t)row * H_F + c4 * 4);
    }
    __syncthreads();
    const int tx = tid & 15, c0 = tx * 4;
    const int ty = tid >> 4, r0 = ty * 4;
    float acc[4][4] = {};
    for (int k = 0; k < H_F; k += 4) {
        float4 wv[4];
#pragma unroll
        for (int kk = 0; kk < 4; ++kk)
            wv[kk] = *(const float4*)(w + (size_t)(k + kk) * OUT_F + c0);
#pragma unroll
        for (int i = 0; i < 4; ++i) {
            float4 av = *(const float4*)(&hs[r0 + i][k]);
            const float* ap = (const float*)&av;
#pragma unroll
            for (int kk = 0; kk < 4; ++kk) {
                acc[i][0] += ap[kk] * wv[kk].x;
                acc[i][1] += ap[kk] * wv[kk].y;
                acc[i][2] += ap[kk] * wv[kk].z;
                acc[i][3] += ap[kk] * wv[kk].w;
            }
        }
    }
    float4 bv = *(const float4*)(b + c0);
#pragma unroll
    for (int i = 0; i < 4; ++i) {
        int row = min(row0 + r0 + i, N_NODES - 1);
        *(float4*)(out + (size_t)row * OUT_F + c0) =
            make_float4(acc[i][0] + bv.x, acc[i][1] + bv.y, acc[i][2] + bv.z, acc[i][3] + bv.w);
    }
}

extern "C" void kernel_launch(void* const* d_in, const int* in_sizes, int n_in,
                              void* d_out, int out_size, void* d_ws, size_t ws_size,
                              hipStream_t stream) {
    const float* x       = (const float*)d_in[0];
    const int*   ei      = (const int*)d_in[1];
    const float* lin0_w  = (const float*)d_in[2];
    const float* lin0_b  = (const float*)d_in[3];
    const float* conv_wl = (const float*)d_in[4];
    const float* conv_bl = (const float*)d_in[5];
    const float* conv_wr = (const float*)d_in[6];
    const float* lin1_w  = (const float*)d_in[7];
    const float* lin1_b  = (const float*)d_in[8];
    float* out = (float*)d_out;

    const size_t NPAD = 50048;  // 64-aligned
    char* ws = (char*)d_ws;
    size_t off = 0;
    auto alloc = [&](size_t bytes) {
        void* p = ws + off;
        off = (off + bytes + 255) & ~(size_t)255;
        return p;
    };
    int*   cursor  = (int*)alloc((size_t)N_NODES * 4);
    int*   row_ptr = (int*)alloc((size_t)(N_NODES + 1) * 4);
    int*   esrc    = (int*)alloc((size_t)E_EDGES * 4);
    int*   tmp     = (int*)alloc((size_t)NB_SCAN * 1024 * 4);
    int*   bsum    = (int*)alloc(64 * 4);
    float* buf0    = (float*)alloc(NPAD * H_F * 4);
    float* buf1    = (float*)alloc(NPAD * H_F * 4);
    unsigned short* hb = (unsigned short*)alloc(NPAD * H_F * 2);

    // ---- CSR ----
    hipMemsetAsync(cursor, 0, (size_t)N_NODES * 4, stream);
    count_kernel<<<(E_EDGES + 255) / 256, 256, 0, stream>>>(ei + E_EDGES, cursor);
    scanA_kernel<<<NB_SCAN, 1024, 0, stream>>>(cursor, tmp, bsum);
    scanB_kernel<<<1, 64, 0, stream>>>(bsum);
    scanC_kernel<<<NB_SCAN, 1024, 0, stream>>>(tmp, bsum, cursor, row_ptr);
    place_kernel<<<(E_EDGES + 255) / 256, 256, 0, stream>>>(ei, cursor, esrc);

    const int gemm_grid = (N_NODES + 63) / 64;  // 782

    // ---- lin0 ----
    lin0_gemm<<<gemm_grid, 512, 0, stream>>>(x, lin0_w, lin0_b, buf0, hb);

    // ---- 3 fused layers: agg writes the non-h buffer; conv_gemm runs in-place ----
    float* h = buf0;
    float* other = buf1;
    for (int l = 0; l < L_LAYERS; ++l) {
        agg_kernel<<<N_NODES / 4, 256, 0, stream>>>(hb, row_ptr, esrc, other);
        conv_gemm<<<gemm_grid, 512, 0, stream>>>(other, h,
                                                 conv_wl + (size_t)l * H_F * H_F,
                                                 conv_wr + (size_t)l * H_F * H_F,
                                                 conv_bl + (size_t)l * H_F,
                                                 hb);
        float* t = h; h = other; other = t;
    }

    // ---- lin1 ----
    lin1_gemm<<<gemm_grid, 256, 0, stream>>>(h, lin1_w, lin1_b, out);
}

// Round 5
// 441.810 us; speedup vs baseline: 3.5243x; 1.4511x over previous
//
#include <hip/hip_runtime.h>
#include <hip/hip_bf16.h>

#define N_NODES 50000
#define E_EDGES 800000
#define IN_F 256
#define H_F 128
#define OUT_F 64
#define L_LAYERS 3
#define NB_SCAN 49   // ceil(50000/1024)

typedef __attribute__((ext_vector_type(8))) short bf16x8;
typedef __attribute__((ext_vector_type(4))) float f32x4;

static __device__ __forceinline__ float bf2f(unsigned short u) {
    return __uint_as_float(((unsigned int)u) << 16);
}
static __device__ __forceinline__ unsigned short f2bf(float f) {
    unsigned int b = __float_as_uint(f);
    return (unsigned short)((b + 0x7FFFu + ((b >> 16) & 1u)) >> 16);  // RTN-even
}

// ================= CSR build =================
__global__ void count_kernel(const int* __restrict__ dst, int* __restrict__ cnt) {
    int e = blockIdx.x * blockDim.x + threadIdx.x;
    if (e < E_EDGES) atomicAdd(&cnt[dst[e]], 1);
}

__global__ __launch_bounds__(1024) void scanA_kernel(const int* __restrict__ cnt,
                                                     int* __restrict__ tmp,
                                                     int* __restrict__ bsum) {
    __shared__ int buf[1024];
    const int tid = threadIdx.x;
    const int i = blockIdx.x * 1024 + tid;
    int v = (i < N_NODES) ? cnt[i] : 0;
    buf[tid] = v;
    __syncthreads();
    for (int off = 1; off < 1024; off <<= 1) {
        int t = (tid >= off) ? buf[tid - off] : 0;
        __syncthreads();
        buf[tid] += t;
        __syncthreads();
    }
    tmp[i] = buf[tid];
    if (tid == 1023) bsum[blockIdx.x] = buf[1023];
}

__global__ void scanB_kernel(int* __restrict__ bsum) {
    int t = threadIdx.x;  // 64
    int v = (t < NB_SCAN) ? bsum[t] : 0;
    int incl = v;
    for (int off = 1; off < 64; off <<= 1) {
        int u = __shfl_up(incl, off, 64);
        if (t >= off) incl += u;
    }
    if (t < NB_SCAN) bsum[t] = incl - v;  // exclusive
}

__global__ __launch_bounds__(1024) void scanC_kernel(const int* __restrict__ tmp,
                                                     const int* __restrict__ bsum,
                                                     int* __restrict__ cursor,  // holds cnt on entry
                                                     int* __restrict__ row_ptr) {
    const int i = blockIdx.x * 1024 + threadIdx.x;
    if (i < N_NODES) {
        int incl = tmp[i] + bsum[i >> 10];
        row_ptr[i + 1] = incl;
        cursor[i] = incl - cursor[i];  // exclusive start
    }
    if (i == 0) row_ptr[0] = 0;
}

__global__ void place_kernel(const int* __restrict__ ei, int* __restrict__ cursor,
                             int* __restrict__ esrc) {
    int e = blockIdx.x * blockDim.x + threadIdx.x;
    if (e < E_EDGES) {
        int s = ei[e];
        int d = ei[E_EDGES + e];
        int pos = atomicAdd(&cursor[d], 1);
        esrc[pos] = s;
    }
}

// ================= weight prep: convert + swizzle to fragment layout =================
// dst[((kb*4+g)*C + c)*8 + j] = bf16(src[(kb*32+g*8+j)*C + c])
__global__ void prep_w(const float* __restrict__ src, unsigned short* __restrict__ dst,
                       int K, int C) {
    int idx = blockIdx.x * 256 + threadIdx.x;
    if (idx >= K * C) return;
    int j = idx & 7;
    int rest = idx >> 3;
    int c = rest % C;
    int gg = rest / C;
    int k = gg * 8 + j;
    dst[idx] = f2bf(src[(size_t)k * C + c]);
}

// dual: virtual B = [wl ; wr], K=256, C=128
__global__ void prep_w_dual(const float* __restrict__ wl, const float* __restrict__ wr,
                            unsigned short* __restrict__ dst) {
    int idx = blockIdx.x * 256 + threadIdx.x;
    if (idx >= 256 * 128) return;
    int j = idx & 7;
    int rest = idx >> 3;
    int c = rest & 127;
    int gg = rest >> 7;
    int k = gg * 8 + j;
    float v = (k < 128) ? wl[(size_t)k * 128 + c] : wr[(size_t)(k - 128) * 128 + c];
    dst[idx] = f2bf(v);
}

// ================= aggregation: Gb[n] = bf16(mean_{src} hb[src]) =================
__global__ __launch_bounds__(256, 8) void agg_kernel(
        const unsigned short* __restrict__ hb, const int* __restrict__ row_ptr,
        const int* __restrict__ esrc, unsigned short* __restrict__ Gb) {
    const int wid = (blockIdx.x * 256 + threadIdx.x) >> 6;  // node
    const int lane = threadIdx.x & 63;
    const int p = lane >> 5;
    const int q = lane & 31;
    const int s0 = row_ptr[wid];
    const int s1 = row_ptr[wid + 1];
    float a0 = 0.f, a1 = 0.f, a2 = 0.f, a3 = 0.f;
    int j = s0;
    for (; j + 4 <= s1; j += 4) {
        int sa = esrc[j + p];
        int sb = esrc[j + p + 2];
        ushort4 va = *(const ushort4*)(hb + ((size_t)sa << 7) + (q << 2));
        ushort4 vb = *(const ushort4*)(hb + ((size_t)sb << 7) + (q << 2));
        a0 += bf2f(va.x) + bf2f(vb.x);
        a1 += bf2f(va.y) + bf2f(vb.y);
        a2 += bf2f(va.z) + bf2f(vb.z);
        a3 += bf2f(va.w) + bf2f(vb.w);
    }
    if (j + p < s1) {
        ushort4 v = *(const ushort4*)(hb + ((size_t)esrc[j + p] << 7) + (q << 2));
        a0 += bf2f(v.x); a1 += bf2f(v.y); a2 += bf2f(v.z); a3 += bf2f(v.w);
    }
    if (j + p + 2 < s1) {
        ushort4 v = *(const ushort4*)(hb + ((size_t)esrc[j + p + 2] << 7) + (q << 2));
        a0 += bf2f(v.x); a1 += bf2f(v.y); a2 += bf2f(v.z); a3 += bf2f(v.w);
    }
    a0 += __shfl(a0, lane ^ 32);
    a1 += __shfl(a1, lane ^ 32);
    a2 += __shfl(a2, lane ^ 32);
    a3 += __shfl(a3, lane ^ 32);
    if (p == 0) {
        float dinv = 1.0f / (float)max(s1 - s0, 1);
        ushort4 o = {f2bf(a0 * dinv), f2bf(a1 * dinv), f2bf(a2 * dinv), f2bf(a3 * dinv)};
        *(ushort4*)(Gb + ((size_t)wid << 7) + (q << 2)) = o;
    }
}

// ================= MFMA GEMM kernels =================
// Block 256 (4 waves), wave owns 64 rows = 4 row-tiles x 16; col-tiles of 16.
// A-frag: row=lane&15, k=kb*32+(lane>>4)*8+j (contiguous 16B). B from pre-swizzled Bp.
// D: col=lane&15, row=(lane>>4)*4+i.

// lin0: A = x (fp32, converted in-register), K=256, C=128, relu, out bf16
__global__ __launch_bounds__(256, 2) void lin0_mfma(
        const float* __restrict__ x, const unsigned short* __restrict__ Bp,
        const float* __restrict__ bias, unsigned short* __restrict__ hb) {
    const int tid = threadIdx.x;
    const int wave = tid >> 6, lane = tid & 63;
    const int g = lane >> 4, r = lane & 15;
    const int row_base = blockIdx.x * 256 + wave * 64;
    f32x4 acc[4][8] = {};
    for (int kb = 0; kb < 8; ++kb) {
        bf16x8 afr[4];
#pragma unroll
        for (int rt = 0; rt < 4; ++rt) {
            int row = min(row_base + rt * 16 + r, N_NODES - 1);
            const float* ap = x + (size_t)row * IN_F + kb * 32 + g * 8;
            float4 v0 = *(const float4*)ap;
            float4 v1 = *(const float4*)(ap + 4);
            afr[rt][0] = (short)f2bf(v0.x); afr[rt][1] = (short)f2bf(v0.y);
            afr[rt][2] = (short)f2bf(v0.z); afr[rt][3] = (short)f2bf(v0.w);
            afr[rt][4] = (short)f2bf(v1.x); afr[rt][5] = (short)f2bf(v1.y);
            afr[rt][6] = (short)f2bf(v1.z); afr[rt][7] = (short)f2bf(v1.w);
        }
#pragma unroll
        for (int ct = 0; ct < 8; ++ct) {
            bf16x8 bfr = *(const bf16x8*)(Bp + ((size_t)((kb * 4 + g) * H_F) + ct * 16 + r) * 8);
#pragma unroll
            for (int rt = 0; rt < 4; ++rt)
                acc[rt][ct] = __builtin_amdgcn_mfma_f32_16x16x32_bf16(afr[rt], bfr, acc[rt][ct], 0, 0, 0);
        }
    }
#pragma unroll
    for (int ct = 0; ct < 8; ++ct) {
        int col = ct * 16 + r;
        float bv = bias[col];
#pragma unroll
        for (int rt = 0; rt < 4; ++rt)
#pragma unroll
            for (int i = 0; i < 4; ++i) {
                int row = row_base + rt * 16 + g * 4 + i;
                if (row < N_NODES)
                    hb[(size_t)row * H_F + col] = f2bf(fmaxf(acc[rt][ct][i] + bv, 0.f));
            }
    }
}

// conv: dual GEMM, A = [Gb | hb] (bf16), K=256, C=128, relu, out bf16
__global__ __launch_bounds__(256, 2) void conv_mfma(
        const unsigned short* __restrict__ Gb, const unsigned short* __restrict__ hb,
        const unsigned short* __restrict__ Bp, const float* __restrict__ bias,
        unsigned short* __restrict__ hbout) {
    const int tid = threadIdx.x;
    const int wave = tid >> 6, lane = tid & 63;
    const int g = lane >> 4, r = lane & 15;
    const int row_base = blockIdx.x * 256 + wave * 64;
    f32x4 acc[4][8] = {};
    for (int kb = 0; kb < 8; ++kb) {
        const unsigned short* Aptr = (kb < 4) ? Gb : hb;
        const int ko = (kb & 3) * 32 + g * 8;
        bf16x8 afr[4];
#pragma unroll
        for (int rt = 0; rt < 4; ++rt) {
            int row = min(row_base + rt * 16 + r, N_NODES - 1);
            afr[rt] = *(const bf16x8*)(Aptr + (size_t)row * H_F + ko);
        }
#pragma unroll
        for (int ct = 0; ct < 8; ++ct) {
            bf16x8 bfr = *(const bf16x8*)(Bp + ((size_t)((kb * 4 + g) * H_F) + ct * 16 + r) * 8);
#pragma unroll
            for (int rt = 0; rt < 4; ++rt)
                acc[rt][ct] = __builtin_amdgcn_mfma_f32_16x16x32_bf16(afr[rt], bfr, acc[rt][ct], 0, 0, 0);
        }
    }
#pragma unroll
    for (int ct = 0; ct < 8; ++ct) {
        int col = ct * 16 + r;
        float bv = bias[col];
#pragma unroll
        for (int rt = 0; rt < 4; ++rt)
#pragma unroll
            for (int i = 0; i < 4; ++i) {
                int row = row_base + rt * 16 + g * 4 + i;
                if (row < N_NODES)
                    hbout[(size_t)row * H_F + col] = f2bf(fmaxf(acc[rt][ct][i] + bv, 0.f));
            }
    }
}

// lin1: A = hb, K=128, C=64, no relu, out fp32
__global__ __launch_bounds__(256, 2) void lin1_mfma(
        const unsigned short* __restrict__ hb, const unsigned short* __restrict__ Bp,
        const float* __restrict__ bias, float* __restrict__ out) {
    const int tid = threadIdx.x;
    const int wave = tid >> 6, lane = tid & 63;
    const int g = lane >> 4, r = lane & 15;
    const int row_base = blockIdx.x * 256 + wave * 64;
    f32x4 acc[4][4] = {};
    for (int kb = 0; kb < 4; ++kb) {
        const int ko = kb * 32 + g * 8;
        bf16x8 afr[4];
#pragma unroll
        for (int rt = 0; rt < 4; ++rt) {
            int row = min(row_base + rt * 16 + r, N_NODES - 1);
            afr[rt] = *(const bf16x8*)(hb + (size_t)row * H_F + ko);
        }
#pragma unroll
        for (int ct = 0; ct < 4; ++ct) {
            bf16x8 bfr = *(const bf16x8*)(Bp + ((size_t)((kb * 4 + g) * OUT_F) + ct * 16 + r) * 8);
#pragma unroll
            for (int rt = 0; rt < 4; ++rt)
                acc[rt][ct] = __builtin_amdgcn_mfma_f32_16x16x32_bf16(afr[rt], bfr, acc[rt][ct], 0, 0, 0);
        }
    }
#pragma unroll
    for (int ct = 0; ct < 4; ++ct) {
        int col = ct * 16 + r;
        float bv = bias[col];
#pragma unroll
        for (int rt = 0; rt < 4; ++rt)
#pragma unroll
            for (int i = 0; i < 4; ++i) {
                int row = row_base + rt * 16 + g * 4 + i;
                if (row < N_NODES)
                    out[(size_t)row * OUT_F + col] = acc[rt][ct][i] + bv;
            }
    }
}

extern "C" void kernel_launch(void* const* d_in, const int* in_sizes, int n_in,
                              void* d_out, int out_size, void* d_ws, size_t ws_size,
                              hipStream_t stream) {
    const float* x       = (const float*)d_in[0];
    const int*   ei      = (const int*)d_in[1];
    const float* lin0_w  = (const float*)d_in[2];
    const float* lin0_b  = (const float*)d_in[3];
    const float* conv_wl = (const float*)d_in[4];
    const float* conv_bl = (const float*)d_in[5];
    const float* conv_wr = (const float*)d_in[6];
    const float* lin1_w  = (const float*)d_in[7];
    const float* lin1_b  = (const float*)d_in[8];
    float* out = (float*)d_out;

    const size_t NPAD = 50176;  // 196*256
    char* ws = (char*)d_ws;
    size_t off = 0;
    auto alloc = [&](size_t bytes) {
        void* p = ws + off;
        off = (off + bytes + 255) & ~(size_t)255;
        return p;
    };
    int* cursor  = (int*)alloc((size_t)N_NODES * 4);
    int* row_ptr = (int*)alloc((size_t)(N_NODES + 1) * 4);
    int* esrc    = (int*)alloc((size_t)E_EDGES * 4);
    int* tmp     = (int*)alloc((size_t)NB_SCAN * 1024 * 4);
    int* bsum    = (int*)alloc(64 * 4);
    unsigned short* hb0 = (unsigned short*)alloc(NPAD * H_F * 2);
    unsigned short* hb1 = (unsigned short*)alloc(NPAD * H_F * 2);
    unsigned short* Gb  = (unsigned short*)alloc(NPAD * H_F * 2);
    unsigned short* BpL0 = (unsigned short*)alloc((size_t)IN_F * H_F * 2);
    unsigned short* BpCv[L_LAYERS];
    for (int l = 0; l < L_LAYERS; ++l)
        BpCv[l] = (unsigned short*)alloc((size_t)256 * H_F * 2);
    unsigned short* BpL1 = (unsigned short*)alloc((size_t)H_F * OUT_F * 2);

    // ---- CSR ----
    hipMemsetAsync(cursor, 0, (size_t)N_NODES * 4, stream);
    count_kernel<<<(E_EDGES + 255) / 256, 256, 0, stream>>>(ei + E_EDGES, cursor);
    scanA_kernel<<<NB_SCAN, 1024, 0, stream>>>(cursor, tmp, bsum);
    scanB_kernel<<<1, 64, 0, stream>>>(bsum);
    scanC_kernel<<<NB_SCAN, 1024, 0, stream>>>(tmp, bsum, cursor, row_ptr);
    place_kernel<<<(E_EDGES + 255) / 256, 256, 0, stream>>>(ei, cursor, esrc);

    // ---- weight prep ----
    prep_w<<<(IN_F * H_F + 255) / 256, 256, 0, stream>>>(lin0_w, BpL0, IN_F, H_F);
    for (int l = 0; l < L_LAYERS; ++l)
        prep_w_dual<<<(256 * H_F + 255) / 256, 256, 0, stream>>>(
            conv_wl + (size_t)l * H_F * H_F, conv_wr + (size_t)l * H_F * H_F, BpCv[l]);
    prep_w<<<(H_F * OUT_F + 255) / 256, 256, 0, stream>>>(lin1_w, BpL1, H_F, OUT_F);

    const int gemm_grid = (int)(NPAD / 256);  // 196

    // ---- lin0 ----
    lin0_mfma<<<gemm_grid, 256, 0, stream>>>(x, BpL0, lin0_b, hb0);

    // ---- 3 fused layers ----
    unsigned short* h = hb0;
    unsigned short* nh = hb1;
    for (int l = 0; l < L_LAYERS; ++l) {
        agg_kernel<<<N_NODES / 4, 256, 0, stream>>>(h, row_ptr, esrc, Gb);
        conv_mfma<<<gemm_grid, 256, 0, stream>>>(Gb, h, BpCv[l],
                                                 conv_bl + (size_t)l * H_F, nh);
        unsigned short* t = h; h = nh; nh = t;
    }

    // ---- lin1 ----
    lin1_mfma<<<gemm_grid, 256, 0, stream>>>(h, BpL1, lin1_b, out);
}

// Round 6
// 366.326 us; speedup vs baseline: 4.2505x; 1.2061x over previous
//
#include <hip/hip_runtime.h>
#include <hip/hip_bf16.h>

#define N_NODES 50000
#define E_EDGES 800000
#define IN_F 256
#define H_F 128
#define OUT_F 64
#define L_LAYERS 3
#define NB_SCAN 49    // ceil(50000/1024)
#define LIN0_BLOCKS 196
#define COUNT_BLOCKS 3125  // 800000/256

typedef __attribute__((ext_vector_type(8))) short bf16x8;
typedef __attribute__((ext_vector_type(4))) float f32x4;

static __device__ __forceinline__ float bf2f(unsigned short u) {
    return __uint_as_float(((unsigned int)u) << 16);
}
static __device__ __forceinline__ unsigned short f2bf(float f) {
    unsigned int b = __float_as_uint(f);
    return (unsigned short)((b + 0x7FFFu + ((b >> 16) & 1u)) >> 16);  // RTN-even
}

// ================= scan (row_ptr from cnt) =================
__global__ __launch_bounds__(1024) void scanA_kernel(const int* __restrict__ cnt,
                                                     int* __restrict__ tmp,
                                                     int* __restrict__ bsum) {
    __shared__ int buf[1024];
    const int tid = threadIdx.x;
    const int i = blockIdx.x * 1024 + tid;
    int v = (i < N_NODES) ? cnt[i] : 0;
    buf[tid] = v;
    __syncthreads();
    for (int off = 1; off < 1024; off <<= 1) {
        int t = (tid >= off) ? buf[tid - off] : 0;
        __syncthreads();
        buf[tid] += t;
        __syncthreads();
    }
    tmp[i] = buf[tid];
    if (tid == 1023) bsum[blockIdx.x] = buf[1023];
}

__global__ void scanB_kernel(int* __restrict__ bsum) {
    int t = threadIdx.x;  // 64
    int v = (t < NB_SCAN) ? bsum[t] : 0;
    int incl = v;
    for (int off = 1; off < 64; off <<= 1) {
        int u = __shfl_up(incl, off, 64);
        if (t >= off) incl += u;
    }
    if (t < NB_SCAN) bsum[t] = incl - v;  // exclusive
}

__global__ __launch_bounds__(1024) void scanC_kernel(const int* __restrict__ tmp,
                                                     const int* __restrict__ bsum,
                                                     int* __restrict__ row_ptr) {
    const int i = blockIdx.x * 1024 + threadIdx.x;
    if (i < N_NODES) row_ptr[i + 1] = tmp[i] + bsum[i >> 10];
    if (i == 0) row_ptr[0] = 0;
}

// ================= atomic-free placement =================
__global__ void place2_kernel(const int* __restrict__ ei, const int* __restrict__ row_ptr,
                              const int* __restrict__ rank, int* __restrict__ esrc) {
    int e = blockIdx.x * blockDim.x + threadIdx.x;
    if (e < E_EDGES) {
        int s = ei[e];
        int d = ei[E_EDGES + e];
        esrc[row_ptr[d] + rank[e]] = s;
    }
}

// ================= merged weight prep =================
// Fragment layout: dst[((kb*4+g)*C + c)*8 + j] = bf16(src[(gg*8+j)*C + c]), gg=kb*4+g
__global__ void prep_all(const float* __restrict__ lin0_w, const float* __restrict__ conv_wl,
                         const float* __restrict__ conv_wr, const float* __restrict__ lin1_w,
                         unsigned short* __restrict__ BpL0, unsigned short* __restrict__ BpCv,
                         unsigned short* __restrict__ BpL1) {
    int gid = blockIdx.x * 256 + threadIdx.x;
    if (gid < 32768) {  // lin0: K=256, C=128
        int idx = gid;
        int j = idx & 7, rest = idx >> 3;
        int c = rest & 127, gg = rest >> 7;
        BpL0[idx] = f2bf(lin0_w[(size_t)(gg * 8 + j) * 128 + c]);
    } else if (gid < 32768 + 3 * 32768) {  // conv dual: virtual B=[wl;wr], K=256, C=128
        int t = gid - 32768;
        int l = t >> 15, idx = t & 32767;
        int j = idx & 7, rest = idx >> 3;
        int c = rest & 127, gg = rest >> 7;
        int k = gg * 8 + j;
        const float* wl = conv_wl + (size_t)l * 16384;
        const float* wr = conv_wr + (size_t)l * 16384;
        float v = (k < 128) ? wl[(size_t)k * 128 + c] : wr[(size_t)(k - 128) * 128 + c];
        BpCv[t] = f2bf(v);
    } else if (gid < 32768 + 3 * 32768 + 8192) {  // lin1: K=128, C=64
        int idx = gid - (32768 + 3 * 32768);
        int j = idx & 7, rest = idx >> 3;
        int c = rest & 63, gg = rest >> 6;
        BpL1[idx] = f2bf(lin1_w[(size_t)(gg * 8 + j) * 64 + c]);
    }
}

// ================= aggregation: Gb[n] = bf16(mean_{src} hb[src]) =================
// 1 wave/node; 16 lanes x 16B per row, 4 edges in flight, x2 unroll
__global__ __launch_bounds__(256, 8) void agg_kernel(
        const unsigned short* __restrict__ hb, const int* __restrict__ row_ptr,
        const int* __restrict__ esrc, unsigned short* __restrict__ Gb) {
    const int wid = (blockIdx.x * 256 + threadIdx.x) >> 6;  // node
    const int lane = threadIdx.x & 63;
    const int p = lane >> 4;   // 0..3 edge slot
    const int q = lane & 15;   // 16B chunk
    const int s0 = row_ptr[wid];
    const int s1 = row_ptr[wid + 1];
    float a[8] = {};
    int j = s0;
    for (; j + 8 <= s1; j += 8) {
        int ea = esrc[j + p];
        int eb = esrc[j + p + 4];
        bf16x8 va = *(const bf16x8*)(hb + ((size_t)ea << 7) + (q << 3));
        bf16x8 vb = *(const bf16x8*)(hb + ((size_t)eb << 7) + (q << 3));
#pragma unroll
        for (int t = 0; t < 8; ++t)
            a[t] += bf2f((unsigned short)va[t]) + bf2f((unsigned short)vb[t]);
    }
    if (j + p < s1) {
        bf16x8 v = *(const bf16x8*)(hb + ((size_t)esrc[j + p] << 7) + (q << 3));
#pragma unroll
        for (int t = 0; t < 8; ++t) a[t] += bf2f((unsigned short)v[t]);
    }
    if (j + p + 4 < s1) {
        bf16x8 v = *(const bf16x8*)(hb + ((size_t)esrc[j + p + 4] << 7) + (q << 3));
#pragma unroll
        for (int t = 0; t < 8; ++t) a[t] += bf2f((unsigned short)v[t]);
    }
#pragma unroll
    for (int t = 0; t < 8; ++t) {
        a[t] += __shfl_xor(a[t], 16, 64);
        a[t] += __shfl_xor(a[t], 32, 64);
    }
    if (p == 0) {
        float dinv = 1.0f / (float)max(s1 - s0, 1);
        bf16x8 o;
#pragma unroll
        for (int t = 0; t < 8; ++t) o[t] = (short)f2bf(a[t] * dinv);
        *(bf16x8*)(Gb + ((size_t)wid << 7) + (q << 3)) = o;
    }
}

// ================= MFMA GEMM kernels =================
// Wave owns 64 rows = 4 row-tiles x 16; col-tiles of 16.
// A-frag: row=lane&15, k=kb*32+(lane>>4)*8+j. D: col=lane&15, row=(lane>>4)*4+i.

// lin0 (blocks < LIN0_BLOCKS) fused with count+rank pass (remaining blocks)
__global__ __launch_bounds__(256, 2) void lin0_count(
        const float* __restrict__ x, const unsigned short* __restrict__ Bp,
        const float* __restrict__ bias, unsigned short* __restrict__ hb,
        const int* __restrict__ ei, int* __restrict__ cnt, int* __restrict__ rank) {
    if (blockIdx.x >= LIN0_BLOCKS) {
        int e = (blockIdx.x - LIN0_BLOCKS) * 256 + threadIdx.x;
        if (e < E_EDGES) {
            int d = ei[E_EDGES + e];
            rank[e] = atomicAdd(&cnt[d], 1);
        }
        return;
    }
    const int tid = threadIdx.x;
    const int wave = tid >> 6, lane = tid & 63;
    const int g = lane >> 4, r = lane & 15;
    const int row_base = blockIdx.x * 256 + wave * 64;
    f32x4 acc[4][8] = {};
    for (int kb = 0; kb < 8; ++kb) {
        bf16x8 afr[4];
#pragma unroll
        for (int rt = 0; rt < 4; ++rt) {
            int row = min(row_base + rt * 16 + r, N_NODES - 1);
            const float* ap = x + (size_t)row * IN_F + kb * 32 + g * 8;
            float4 v0 = *(const float4*)ap;
            float4 v1 = *(const float4*)(ap + 4);
            afr[rt][0] = (short)f2bf(v0.x); afr[rt][1] = (short)f2bf(v0.y);
            afr[rt][2] = (short)f2bf(v0.z); afr[rt][3] = (short)f2bf(v0.w);
            afr[rt][4] = (short)f2bf(v1.x); afr[rt][5] = (short)f2bf(v1.y);
            afr[rt][6] = (short)f2bf(v1.z); afr[rt][7] = (short)f2bf(v1.w);
        }
#pragma unroll
        for (int ct = 0; ct < 8; ++ct) {
            bf16x8 bfr = *(const bf16x8*)(Bp + ((size_t)((kb * 4 + g) * H_F) + ct * 16 + r) * 8);
#pragma unroll
            for (int rt = 0; rt < 4; ++rt)
                acc[rt][ct] = __builtin_amdgcn_mfma_f32_16x16x32_bf16(afr[rt], bfr, acc[rt][ct], 0, 0, 0);
        }
    }
#pragma unroll
    for (int ct = 0; ct < 8; ++ct) {
        int col = ct * 16 + r;
        float bv = bias[col];
#pragma unroll
        for (int rt = 0; rt < 4; ++rt)
#pragma unroll
            for (int i = 0; i < 4; ++i) {
                int row = row_base + rt * 16 + g * 4 + i;
                if (row < N_NODES)
                    hb[(size_t)row * H_F + col] = f2bf(fmaxf(acc[rt][ct][i] + bv, 0.f));
            }
    }
}

// conv: dual GEMM, A = [Gb | hb] (bf16), K=256, C=128, relu, out bf16
__global__ __launch_bounds__(256, 2) void conv_mfma(
        const unsigned short* __restrict__ Gb, const unsigned short* __restrict__ hb,
        const unsigned short* __restrict__ Bp, const float* __restrict__ bias,
        unsigned short* __restrict__ hbout) {
    const int tid = threadIdx.x;
    const int wave = tid >> 6, lane = tid & 63;
    const int g = lane >> 4, r = lane & 15;
    const int row_base = blockIdx.x * 256 + wave * 64;
    f32x4 acc[4][8] = {};
    for (int kb = 0; kb < 8; ++kb) {
        const unsigned short* Aptr = (kb < 4) ? Gb : hb;
        const int ko = (kb & 3) * 32 + g * 8;
        bf16x8 afr[4];
#pragma unroll
        for (int rt = 0; rt < 4; ++rt) {
            int row = min(row_base + rt * 16 + r, N_NODES - 1);
            afr[rt] = *(const bf16x8*)(Aptr + (size_t)row * H_F + ko);
        }
#pragma unroll
        for (int ct = 0; ct < 8; ++ct) {
            bf16x8 bfr = *(const bf16x8*)(Bp + ((size_t)((kb * 4 + g) * H_F) + ct * 16 + r) * 8);
#pragma unroll
            for (int rt = 0; rt < 4; ++rt)
                acc[rt][ct] = __builtin_amdgcn_mfma_f32_16x16x32_bf16(afr[rt], bfr, acc[rt][ct], 0, 0, 0);
        }
    }
#pragma unroll
    for (int ct = 0; ct < 8; ++ct) {
        int col = ct * 16 + r;
        float bv = bias[col];
#pragma unroll
        for (int rt = 0; rt < 4; ++rt)
#pragma unroll
            for (int i = 0; i < 4; ++i) {
                int row = row_base + rt * 16 + g * 4 + i;
                if (row < N_NODES)
                    hbout[(size_t)row * H_F + col] = f2bf(fmaxf(acc[rt][ct][i] + bv, 0.f));
            }
    }
}

// lin1: A = hb, K=128, C=64, no relu, out fp32
__global__ __launch_bounds__(256, 2) void lin1_mfma(
        const unsigned short* __restrict__ hb, const unsigned short* __restrict__ Bp,
        const float* __restrict__ bias, float* __restrict__ out) {
    const int tid = threadIdx.x;
    const int wave = tid >> 6, lane = tid & 63;
    const int g = lane >> 4, r = lane & 15;
    const int row_base = blockIdx.x * 256 + wave * 64;
    f32x4 acc[4][4] = {};
    for (int kb = 0; kb < 4; ++kb) {
        const int ko = kb * 32 + g * 8;
        bf16x8 afr[4];
#pragma unroll
        for (int rt = 0; rt < 4; ++rt) {
            int row = min(row_base + rt * 16 + r, N_NODES - 1);
            afr[rt] = *(const bf16x8*)(hb + (size_t)row * H_F + ko);
        }
#pragma unroll
        for (int ct = 0; ct < 4; ++ct) {
            bf16x8 bfr = *(const bf16x8*)(Bp + ((size_t)((kb * 4 + g) * OUT_F) + ct * 16 + r) * 8);
#pragma unroll
            for (int rt = 0; rt < 4; ++rt)
                acc[rt][ct] = __builtin_amdgcn_mfma_f32_16x16x32_bf16(afr[rt], bfr, acc[rt][ct], 0, 0, 0);
        }
    }
#pragma unroll
    for (int ct = 0; ct < 4; ++ct) {
        int col = ct * 16 + r;
        float bv = bias[col];
#pragma unroll
        for (int rt = 0; rt < 4; ++rt)
#pragma unroll
            for (int i = 0; i < 4; ++i) {
                int row = row_base + rt * 16 + g * 4 + i;
                if (row < N_NODES)
                    out[(size_t)row * OUT_F + col] = acc[rt][ct][i] + bv;
            }
    }
}

extern "C" void kernel_launch(void* const* d_in, const int* in_sizes, int n_in,
                              void* d_out, int out_size, void* d_ws, size_t ws_size,
                              hipStream_t stream) {
    const float* x       = (const float*)d_in[0];
    const int*   ei      = (const int*)d_in[1];
    const float* lin0_w  = (const float*)d_in[2];
    const float* lin0_b  = (const float*)d_in[3];
    const float* conv_wl = (const float*)d_in[4];
    const float* conv_bl = (const float*)d_in[5];
    const float* conv_wr = (const float*)d_in[6];
    const float* lin1_w  = (const float*)d_in[7];
    const float* lin1_b  = (const float*)d_in[8];
    float* out = (float*)d_out;

    const size_t NPAD = 50176;  // 196*256
    char* ws = (char*)d_ws;
    size_t off = 0;
    auto alloc = [&](size_t bytes) {
        void* p = ws + off;
        off = (off + bytes + 255) & ~(size_t)255;
        return p;
    };
    int* cnt     = (int*)alloc((size_t)N_NODES * 4);
    int* row_ptr = (int*)alloc((size_t)(N_NODES + 1) * 4);
    int* esrc    = (int*)alloc((size_t)E_EDGES * 4);
    int* rank    = (int*)alloc((size_t)E_EDGES * 4);
    int* tmp     = (int*)alloc((size_t)NB_SCAN * 1024 * 4);
    int* bsum    = (int*)alloc(64 * 4);
    unsigned short* hb0  = (unsigned short*)alloc(NPAD * H_F * 2);
    unsigned short* hb1  = (unsigned short*)alloc(NPAD * H_F * 2);
    unsigned short* Gb   = (unsigned short*)alloc(NPAD * H_F * 2);
    unsigned short* BpL0 = (unsigned short*)alloc((size_t)IN_F * H_F * 2);
    unsigned short* BpCv = (unsigned short*)alloc((size_t)L_LAYERS * 256 * H_F * 2);
    unsigned short* BpL1 = (unsigned short*)alloc((size_t)H_F * OUT_F * 2);

    // ---- prep ----
    hipMemsetAsync(cnt, 0, (size_t)N_NODES * 4, stream);
    prep_all<<<544, 256, 0, stream>>>(lin0_w, conv_wl, conv_wr, lin1_w, BpL0, BpCv, BpL1);

    // ---- lin0 GEMM overlapped with edge count+rank ----
    lin0_count<<<LIN0_BLOCKS + COUNT_BLOCKS, 256, 0, stream>>>(
        x, BpL0, lin0_b, hb0, ei, cnt, rank);

    // ---- scan + atomic-free place ----
    scanA_kernel<<<NB_SCAN, 1024, 0, stream>>>(cnt, tmp, bsum);
    scanB_kernel<<<1, 64, 0, stream>>>(bsum);
    scanC_kernel<<<NB_SCAN, 1024, 0, stream>>>(tmp, bsum, row_ptr);
    place2_kernel<<<COUNT_BLOCKS, 256, 0, stream>>>(ei, row_ptr, rank, esrc);

    const int gemm_grid = (int)(NPAD / 256);  // 196

    // ---- 3 fused layers ----
    unsigned short* h = hb0;
    unsigned short* nh = hb1;
    for (int l = 0; l < L_LAYERS; ++l) {
        agg_kernel<<<N_NODES / 4, 256, 0, stream>>>(h, row_ptr, esrc, Gb);
        conv_mfma<<<gemm_grid, 256, 0, stream>>>(Gb, h, BpCv + (size_t)l * 256 * H_F,
                                                 conv_bl + (size_t)l * H_F, nh);
        unsigned short* t = h; h = nh; nh = t;
    }

    // ---- lin1 ----
    lin1_mfma<<<gemm_grid, 256, 0, stream>>>(h, BpL1, lin1_b, out);
}

// Round 8
// 360.350 us; speedup vs baseline: 4.3210x; 1.0166x over previous
//
#include <hip/hip_runtime.h>
#include <hip/hip_bf16.h>

#define N_NODES 50000
#define E_EDGES 800000
#define IN_F 256
#define H_F 128
#define OUT_F 64
#define L_LAYERS 3
#define NB_SCAN 49    // ceil(50000/1024)
#define LIN0_BLOCKS 784
#define COUNT_BLOCKS 3125  // 800000/256
#define NPAD 50176         // 784*64

typedef __attribute__((ext_vector_type(8))) short bf16x8;
typedef __attribute__((ext_vector_type(4))) float f32x4;

static __device__ __forceinline__ float bf2f(unsigned short u) {
    return __uint_as_float(((unsigned int)u) << 16);
}
static __device__ __forceinline__ unsigned short f2bf(float f) {
    unsigned int b = __float_as_uint(f);
    return (unsigned short)((b + 0x7FFFu + ((b >> 16) & 1u)) >> 16);  // RTN-even
}

// ================= scan (row_ptr from strided cnt) =================
__global__ __launch_bounds__(1024) void scanA_kernel(const int* __restrict__ cnt,
                                                     int* __restrict__ tmp,
                                                     int* __restrict__ bsum) {
    __shared__ int buf[1024];
    const int tid = threadIdx.x;
    const int i = blockIdx.x * 1024 + tid;
    int v = (i < N_NODES) ? cnt[(size_t)i << 4] : 0;   // stride-16
    buf[tid] = v;
    __syncthreads();
    for (int off = 1; off < 1024; off <<= 1) {
        int t = (tid >= off) ? buf[tid - off] : 0;
        __syncthreads();
        buf[tid] += t;
        __syncthreads();
    }
    tmp[i] = buf[tid];
    if (tid == 1023) bsum[blockIdx.x] = buf[1023];
}

__global__ void scanB_kernel(int* __restrict__ bsum) {
    int t = threadIdx.x;  // 64
    int v = (t < NB_SCAN) ? bsum[t] : 0;
    int incl = v;
    for (int off = 1; off < 64; off <<= 1) {
        int u = __shfl_up(incl, off, 64);
        if (t >= off) incl += u;
    }
    if (t < NB_SCAN) bsum[t] = incl - v;  // exclusive
}

__global__ __launch_bounds__(1024) void scanC_kernel(const int* __restrict__ tmp,
                                                     const int* __restrict__ bsum,
                                                     int* __restrict__ row_ptr) {
    const int i = blockIdx.x * 1024 + threadIdx.x;
    if (i < N_NODES) row_ptr[i + 1] = tmp[i] + bsum[i >> 10];
    if (i == 0) row_ptr[0] = 0;
}

// ================= atomic-free placement =================
__global__ void place2_kernel(const int* __restrict__ ei, const int* __restrict__ row_ptr,
                              const int* __restrict__ rank, int* __restrict__ esrc) {
    int e = blockIdx.x * blockDim.x + threadIdx.x;
    if (e < E_EDGES) {
        int s = ei[e];
        int d = ei[E_EDGES + e];
        esrc[row_ptr[d] + rank[e]] = s;
    }
}

// ================= merged weight prep =================
// Fragment layout: dst[(gg*C + c)*8 + j] = bf16(src[(gg*8+j)*C + c])
__global__ void prep_all(const float* __restrict__ lin0_w, const float* __restrict__ conv_wl,
                         const float* __restrict__ conv_wr, const float* __restrict__ lin1_w,
                         unsigned short* __restrict__ BpL0, unsigned short* __restrict__ BpCv,
                         unsigned short* __restrict__ BpL1) {
    int gid = blockIdx.x * 256 + threadIdx.x;
    if (gid < 32768) {  // lin0: K=256, C=128
        int idx = gid;
        int j = idx & 7, rest = idx >> 3;
        int c = rest & 127, gg = rest >> 7;
        BpL0[idx] = f2bf(lin0_w[(size_t)(gg * 8 + j) * 128 + c]);
    } else if (gid < 32768 + 3 * 32768) {  // conv dual: virtual B=[wl;wr], K=256, C=128
        int t = gid - 32768;
        int l = t >> 15, idx = t & 32767;
        int j = idx & 7, rest = idx >> 3;
        int c = rest & 127, gg = rest >> 7;
        int k = gg * 8 + j;
        const float* wl = conv_wl + (size_t)l * 16384;
        const float* wr = conv_wr + (size_t)l * 16384;
        float v = (k < 128) ? wl[(size_t)k * 128 + c] : wr[(size_t)(k - 128) * 128 + c];
        BpCv[t] = f2bf(v);
    } else if (gid < 32768 + 3 * 32768 + 8192) {  // lin1: K=128, C=64
        int idx = gid - (32768 + 3 * 32768);
        int j = idx & 7, rest = idx >> 3;
        int c = rest & 63, gg = rest >> 6;
        BpL1[idx] = f2bf(lin1_w[(size_t)(gg * 8 + j) * 64 + c]);
    }
}

// ================= lin0 (64-row blocks) fused with count+rank =================
// A-frag: row=lane&15, k=kb*32+(lane>>4)*8+j. D: col=lane&15, row=(lane>>4)*4+i.
__global__ __launch_bounds__(256, 4) void lin0_count(
        const float* __restrict__ x, const unsigned short* __restrict__ Bp,
        const float* __restrict__ bias, unsigned short* __restrict__ hb,
        const int* __restrict__ ei, int* __restrict__ cnt, int* __restrict__ rank) {
    if (blockIdx.x >= LIN0_BLOCKS) {
        int e = (blockIdx.x - LIN0_BLOCKS) * 256 + threadIdx.x;
        if (e < E_EDGES) {
            int d = ei[E_EDGES + e];
            rank[e] = atomicAdd(&cnt[(size_t)d << 4], 1);  // 1 counter per 64B line
        }
        return;
    }
    const int tid = threadIdx.x;
    const int wave = tid >> 6, lane = tid & 63;
    const int g = lane >> 4, r = lane & 15;
    const int row_base = blockIdx.x * 64 + wave * 16;
    f32x4 acc[8] = {};
    for (int kb = 0; kb < 8; ++kb) {
        int row = min(row_base + r, N_NODES - 1);
        const float* ap = x + (size_t)row * IN_F + kb * 32 + g * 8;
        float4 v0 = *(const float4*)ap;
        float4 v1 = *(const float4*)(ap + 4);
        bf16x8 afr;
        afr[0] = (short)f2bf(v0.x); afr[1] = (short)f2bf(v0.y);
        afr[2] = (short)f2bf(v0.z); afr[3] = (short)f2bf(v0.w);
        afr[4] = (short)f2bf(v1.x); afr[5] = (short)f2bf(v1.y);
        afr[6] = (short)f2bf(v1.z); afr[7] = (short)f2bf(v1.w);
#pragma unroll
        for (int ct = 0; ct < 8; ++ct) {
            bf16x8 bfr = *(const bf16x8*)(Bp + ((size_t)((kb * 4 + g) * H_F) + ct * 16 + r) * 8);
            acc[ct] = __builtin_amdgcn_mfma_f32_16x16x32_bf16(afr, bfr, acc[ct], 0, 0, 0);
        }
    }
#pragma unroll
    for (int ct = 0; ct < 8; ++ct) {
        int col = ct * 16 + r;
        float bv = bias[col];
#pragma unroll
        for (int i = 0; i < 4; ++i) {
            int row = row_base + g * 4 + i;
            if (row < N_NODES)
                hb[(size_t)row * H_F + col] = f2bf(fmaxf(acc[ct][i] + bv, 0.f));
        }
    }
}

// ================= fused SAGEConv: agg (into swizzled LDS) + dual GEMM =================
// Block: 256 thr (4 waves), 64 rows. Wave w aggregates nodes [w*16, w*16+16), then
// computes rows [w*16, w*16+16) x 128 cols, K=256 (agg from LDS, self from global).
__global__ __launch_bounds__(256, 4) void conv_fused(
        const unsigned short* __restrict__ hb, const int* __restrict__ row_ptr,
        const int* __restrict__ esrc, const unsigned short* __restrict__ Bp,
        const float* __restrict__ bias, unsigned short* __restrict__ hbout) {
    __shared__ unsigned short sAgg[64 * 128];  // 16KB, XOR-swizzled 16B chunks
    const int tid = threadIdx.x;
    const int wave = tid >> 6, lane = tid & 63;
    const int row0 = blockIdx.x * 64;

    // ---- aggregation phase ----
    {
        const int p = lane >> 4;   // edge slot 0..3
        const int q = lane & 15;   // 16B chunk
        for (int i = 0; i < 16; ++i) {
            const int ln = wave * 16 + i;
            const int node = row0 + ln;
            int s0 = 0, s1 = 0;
            if (node < N_NODES) { s0 = row_ptr[node]; s1 = row_ptr[node + 1]; }
            float a[8] = {};
            int j = s0;
            for (; j + 8 <= s1; j += 8) {
                int ea = esrc[j + p];
                int eb = esrc[j + p + 4];
                bf16x8 va = *(const bf16x8*)(hb + ((size_t)ea << 7) + (q << 3));
                bf16x8 vb = *(const bf16x8*)(hb + ((size_t)eb << 7) + (q << 3));
#pragma unroll
                for (int t = 0; t < 8; ++t)
                    a[t] += bf2f((unsigned short)va[t]) + bf2f((unsigned short)vb[t]);
            }
            if (j + p < s1) {
                bf16x8 v = *(const bf16x8*)(hb + ((size_t)esrc[j + p] << 7) + (q << 3));
#pragma unroll
                for (int t = 0; t < 8; ++t) a[t] += bf2f((unsigned short)v[t]);
            }
            if (j + p + 4 < s1) {
                bf16x8 v = *(const bf16x8*)(hb + ((size_t)esrc[j + p + 4] << 7) + (q << 3));
#pragma unroll
                for (int t = 0; t < 8; ++t) a[t] += bf2f((unsigned short)v[t]);
            }
#pragma unroll
            for (int t = 0; t < 8; ++t) {
                a[t] += __shfl_xor(a[t], 16, 64);
                a[t] += __shfl_xor(a[t], 32, 64);
            }
            if (p == 0) {
                float dinv = 1.0f / (float)max(s1 - s0, 1);
                bf16x8 o;
#pragma unroll
                for (int t = 0; t < 8; ++t) o[t] = (short)f2bf(a[t] * dinv);
                int c16 = q ^ (ln & 7);  // swizzle
                *(bf16x8*)(sAgg + ln * 128 + (c16 << 3)) = o;
            }
        }
    }
    __syncthreads();

    // ---- dual GEMM phase ----
    const int g = lane >> 4, r = lane & 15;
    const int row_base = row0 + wave * 16;
    f32x4 acc[8] = {};
    for (int kb = 0; kb < 8; ++kb) {
        bf16x8 afr;
        if (kb < 4) {  // agg operand from LDS (swizzled)
            int c16 = (kb * 4 + g) ^ (r & 7);
            afr = *(const bf16x8*)(sAgg + (wave * 16 + r) * 128 + (c16 << 3));
        } else {       // self operand from global
            int row = min(row_base + r, N_NODES - 1);
            afr = *(const bf16x8*)(hb + (size_t)row * H_F + (kb & 3) * 32 + g * 8);
        }
#pragma unroll
        for (int ct = 0; ct < 8; ++ct) {
            bf16x8 bfr = *(const bf16x8*)(Bp + ((size_t)((kb * 4 + g) * H_F) + ct * 16 + r) * 8);
            acc[ct] = __builtin_amdgcn_mfma_f32_16x16x32_bf16(afr, bfr, acc[ct], 0, 0, 0);
        }
    }
#pragma unroll
    for (int ct = 0; ct < 8; ++ct) {
        int col = ct * 16 + r;
        float bv = bias[col];
#pragma unroll
        for (int i = 0; i < 4; ++i) {
            int row = row_base + g * 4 + i;
            if (row < N_NODES)
                hbout[(size_t)row * H_F + col] = f2bf(fmaxf(acc[ct][i] + bv, 0.f));
        }
    }
}

// ================= lin1 (64-row blocks): out = hb @ W + b, fp32 =================
__global__ __launch_bounds__(256, 4) void lin1_mfma(
        const unsigned short* __restrict__ hb, const unsigned short* __restrict__ Bp,
        const float* __restrict__ bias, float* __restrict__ out) {
    const int tid = threadIdx.x;
    const int wave = tid >> 6, lane = tid & 63;
    const int g = lane >> 4, r = lane & 15;
    const int row_base = blockIdx.x * 64 + wave * 16;
    f32x4 acc[4] = {};
    for (int kb = 0; kb < 4; ++kb) {
        int row = min(row_base + r, N_NODES - 1);
        bf16x8 afr = *(const bf16x8*)(hb + (size_t)row * H_F + kb * 32 + g * 8);
#pragma unroll
        for (int ct = 0; ct < 4; ++ct) {
            bf16x8 bfr = *(const bf16x8*)(Bp + ((size_t)((kb * 4 + g) * OUT_F) + ct * 16 + r) * 8);
            acc[ct] = __builtin_amdgcn_mfma_f32_16x16x32_bf16(afr, bfr, acc[ct], 0, 0, 0);
        }
    }
#pragma unroll
    for (int ct = 0; ct < 4; ++ct) {
        int col = ct * 16 + r;
        float bv = bias[col];
#pragma unroll
        for (int i = 0; i < 4; ++i) {
            int row = row_base + g * 4 + i;
            if (row < N_NODES)
                out[(size_t)row * OUT_F + col] = acc[ct][i] + bv;
        }
    }
}

extern "C" void kernel_launch(void* const* d_in, const int* in_sizes, int n_in,
                              void* d_out, int out_size, void* d_ws, size_t ws_size,
                              hipStream_t stream) {
    const float* x       = (const float*)d_in[0];
    const int*   ei      = (const int*)d_in[1];
    const float* lin0_w  = (const float*)d_in[2];
    const float* lin0_b  = (const float*)d_in[3];
    const float* conv_wl = (const float*)d_in[4];
    const float* conv_bl = (const float*)d_in[5];
    const float* conv_wr = (const float*)d_in[6];
    const float* lin1_w  = (const float*)d_in[7];
    const float* lin1_b  = (const float*)d_in[8];
    float* out = (float*)d_out;

    char* ws = (char*)d_ws;
    size_t off = 0;
    auto alloc = [&](size_t bytes) {
        void* p = ws + off;
        off = (off + bytes + 255) & ~(size_t)255;
        return p;
    };
    int* cnt     = (int*)alloc((size_t)N_NODES * 16 * 4);  // stride-16: 1 counter / 64B line
    int* row_ptr = (int*)alloc((size_t)(N_NODES + 1) * 4);
    int* esrc    = (int*)alloc((size_t)E_EDGES * 4);
    int* rank    = (int*)alloc((size_t)E_EDGES * 4);
    int* tmp     = (int*)alloc((size_t)NB_SCAN * 1024 * 4);
    int* bsum    = (int*)alloc(64 * 4);
    unsigned short* hb0  = (unsigned short*)alloc((size_t)NPAD * H_F * 2);
    unsigned short* hb1  = (unsigned short*)alloc((size_t)NPAD * H_F * 2);
    unsigned short* BpL0 = (unsigned short*)alloc((size_t)IN_F * H_F * 2);
    unsigned short* BpCv = (unsigned short*)alloc((size_t)L_LAYERS * 256 * H_F * 2);
    unsigned short* BpL1 = (unsigned short*)alloc((size_t)H_F * OUT_F * 2);

    // ---- prep ----
    hipMemsetAsync(cnt, 0, (size_t)N_NODES * 16 * 4, stream);
    prep_all<<<544, 256, 0, stream>>>(lin0_w, conv_wl, conv_wr, lin1_w, BpL0, BpCv, BpL1);

    // ---- lin0 GEMM overlapped with edge count+rank ----
    lin0_count<<<LIN0_BLOCKS + COUNT_BLOCKS, 256, 0, stream>>>(
        x, BpL0, lin0_b, hb0, ei, cnt, rank);

    // ---- scan + atomic-free place ----
    scanA_kernel<<<NB_SCAN, 1024, 0, stream>>>(cnt, tmp, bsum);
    scanB_kernel<<<1, 64, 0, stream>>>(bsum);
    scanC_kernel<<<NB_SCAN, 1024, 0, stream>>>(tmp, bsum, row_ptr);
    place2_kernel<<<COUNT_BLOCKS, 256, 0, stream>>>(ei, row_ptr, rank, esrc);

    // ---- 3 fused agg+conv layers ----
    unsigned short* h = hb0;
    unsigned short* nh = hb1;
    for (int l = 0; l < L_LAYERS; ++l) {
        conv_fused<<<NPAD / 64, 256, 0, stream>>>(h, row_ptr, esrc,
                                                  BpCv + (size_t)l * 256 * H_F,
                                                  conv_bl + (size_t)l * H_F, nh);
        unsigned short* t = h; h = nh; nh = t;
    }

    // ---- lin1 ----
    lin1_mfma<<<NPAD / 64, 256, 0, stream>>>(h, BpL1, lin1_b, out);
}

// Round 10
// 310.783 us; speedup vs baseline: 5.0101x; 1.1595x over previous
//
#include <hip/hip_runtime.h>
#include <hip/hip_bf16.h>

#define N_NODES 50000
#define E_EDGES 800000
#define IN_F 256
#define H_F 128
#define OUT_F 64
#define L_LAYERS 3
#define NB_SCAN 49    // ceil(50000/1024)
#define LIN0_BLOCKS 784    // 64-row blocks
#define COUNT_BLOCKS 3125  // 800000/256
#define NPAD 50176         // 784*64 = 1568*32

typedef __attribute__((ext_vector_type(8))) short bf16x8;
typedef __attribute__((ext_vector_type(4))) float f32x4;

static __device__ __forceinline__ float bf2f(unsigned short u) {
    return __uint_as_float(((unsigned int)u) << 16);
}
static __device__ __forceinline__ unsigned short f2bf(float f) {
    unsigned int b = __float_as_uint(f);
    return (unsigned short)((b + 0x7FFFu + ((b >> 16) & 1u)) >> 16);  // RTN-even
}

// ================= scan (row_ptr from strided cnt) =================
__global__ __launch_bounds__(1024) void scanA_kernel(const int* __restrict__ cnt,
                                                     int* __restrict__ tmp,
                                                     int* __restrict__ bsum) {
    __shared__ int buf[1024];
    const int tid = threadIdx.x;
    const int i = blockIdx.x * 1024 + tid;
    int v = (i < N_NODES) ? cnt[(size_t)i << 4] : 0;   // stride-16
    buf[tid] = v;
    __syncthreads();
    for (int off = 1; off < 1024; off <<= 1) {
        int t = (tid >= off) ? buf[tid - off] : 0;
        __syncthreads();
        buf[tid] += t;
        __syncthreads();
    }
    tmp[i] = buf[tid];
    if (tid == 1023) bsum[blockIdx.x] = buf[1023];
}

__global__ void scanB_kernel(int* __restrict__ bsum) {
    int t = threadIdx.x;  // 64
    int v = (t < NB_SCAN) ? bsum[t] : 0;
    int incl = v;
    for (int off = 1; off < 64; off <<= 1) {
        int u = __shfl_up(incl, off, 64);
        if (t >= off) incl += u;
    }
    if (t < NB_SCAN) bsum[t] = incl - v;  // exclusive
}

__global__ __launch_bounds__(1024) void scanC_kernel(const int* __restrict__ tmp,
                                                     const int* __restrict__ bsum,
                                                     int* __restrict__ row_ptr) {
    const int i = blockIdx.x * 1024 + threadIdx.x;
    if (i < N_NODES) row_ptr[i + 1] = tmp[i] + bsum[i >> 10];
    if (i == 0) row_ptr[0] = 0;
}

// ================= atomic-free placement =================
__global__ void place2_kernel(const int* __restrict__ ei, const int* __restrict__ row_ptr,
                              const int* __restrict__ rank, int* __restrict__ esrc) {
    int e = blockIdx.x * blockDim.x + threadIdx.x;
    if (e < E_EDGES) {
        int s = ei[e];
        int d = ei[E_EDGES + e];
        esrc[row_ptr[d] + rank[e]] = s;
    }
}

// ================= merged weight prep =================
// Fragment layout: dst[(gg*C + c)*8 + j] = bf16(src[(gg*8+j)*C + c])
__global__ void prep_all(const float* __restrict__ lin0_w, const float* __restrict__ conv_wl,
                         const float* __restrict__ conv_wr, const float* __restrict__ lin1_w,
                         unsigned short* __restrict__ BpL0, unsigned short* __restrict__ BpCv,
                         unsigned short* __restrict__ BpL1) {
    int gid = blockIdx.x * 256 + threadIdx.x;
    if (gid < 32768) {  // lin0: K=256, C=128
        int idx = gid;
        int j = idx & 7, rest = idx >> 3;
        int c = rest & 127, gg = rest >> 7;
        BpL0[idx] = f2bf(lin0_w[(size_t)(gg * 8 + j) * 128 + c]);
    } else if (gid < 32768 + 3 * 32768) {  // conv dual: virtual B=[wl;wr], K=256, C=128
        int t = gid - 32768;
        int l = t >> 15, idx = t & 32767;
        int j = idx & 7, rest = idx >> 3;
        int c = rest & 127, gg = rest >> 7;
        int k = gg * 8 + j;
        const float* wl = conv_wl + (size_t)l * 16384;
        const float* wr = conv_wr + (size_t)l * 16384;
        float v = (k < 128) ? wl[(size_t)k * 128 + c] : wr[(size_t)(k - 128) * 128 + c];
        BpCv[t] = f2bf(v);
    } else if (gid < 32768 + 3 * 32768 + 8192) {  // lin1: K=128, C=64
        int idx = gid - (32768 + 3 * 32768);
        int j = idx & 7, rest = idx >> 3;
        int c = rest & 63, gg = rest >> 6;
        BpL1[idx] = f2bf(lin1_w[(size_t)(gg * 8 + j) * 64 + c]);
    }
}

// ================= lin0 (count blocks FIRST, then 64-row GEMM blocks) =================
// A-frag: row=lane&15, k=kb*32+(lane>>4)*8+j. D: col=lane&15, row=(lane>>4)*4+i.
__global__ __launch_bounds__(256, 3) void lin0_count(
        const float* __restrict__ x, const unsigned short* __restrict__ Bp,
        const float* __restrict__ bias, unsigned short* __restrict__ hb,
        const int* __restrict__ ei, int* __restrict__ cnt, int* __restrict__ rank) {
    if (blockIdx.x < COUNT_BLOCKS) {
        int e = blockIdx.x * 256 + threadIdx.x;
        if (e < E_EDGES) {
            int d = ei[E_EDGES + e];
            rank[e] = atomicAdd(&cnt[(size_t)d << 4], 1);  // 1 counter per 64B line
        }
        return;
    }
    const int gb = blockIdx.x - COUNT_BLOCKS;
    const int tid = threadIdx.x;
    const int wave = tid >> 6, lane = tid & 63;
    const int g = lane >> 4, r = lane & 15;
    const int row_base = gb * 64 + wave * 16;
    const int row = min(row_base + r, N_NODES - 1);
    const float* xp = x + (size_t)row * IN_F + g * 8;
    // 16-deep prefetch: whole 256-wide slice for this lane
    float4 xv[16];
#pragma unroll
    for (int t = 0; t < 16; ++t)
        xv[t] = *(const float4*)(xp + (t >> 1) * 32 + (t & 1) * 4);
    f32x4 acc[8] = {};
#pragma unroll
    for (int kb = 0; kb < 8; ++kb) {
        const float* v0 = (const float*)&xv[kb * 2];
        bf16x8 afr;
#pragma unroll
        for (int t = 0; t < 8; ++t) afr[t] = (short)f2bf(v0[t]);
#pragma unroll
        for (int ct = 0; ct < 8; ++ct) {
            bf16x8 bfr = *(const bf16x8*)(Bp + ((size_t)(kb * 4 + g) * H_F + ct * 16 + r) * 8);
            acc[ct] = __builtin_amdgcn_mfma_f32_16x16x32_bf16(afr, bfr, acc[ct], 0, 0, 0);
        }
    }
#pragma unroll
    for (int ct = 0; ct < 8; ++ct) {
        int col = ct * 16 + r;
        float bv = bias[col];
#pragma unroll
        for (int i = 0; i < 4; ++i) {
            int orow = row_base + g * 4 + i;
            if (orow < N_NODES)
                hb[(size_t)orow * H_F + col] = f2bf(fmaxf(acc[ct][i] + bv, 0.f));
        }
    }
}

// ================= fused SAGEConv: 32-row blocks, MLP-4 agg + dual GEMM =================
// 256 thr (4 waves). Agg: wave w aggregates nodes w*8..w*8+7 into swizzled LDS.
// GEMM: wave w -> row-tile (w&1), col-half (w>>1); K=256 (agg from LDS, self prefetched).
__global__ __launch_bounds__(256, 4) void conv_fused(
        const unsigned short* __restrict__ hb, const int* __restrict__ row_ptr,
        const int* __restrict__ esrc, const unsigned short* __restrict__ Bp,
        const float* __restrict__ bias, unsigned short* __restrict__ hbout) {
    __shared__ unsigned short sAgg[32 * 128];  // 8KB, XOR-swizzled 16B chunks
    const int tid = threadIdx.x;
    const int wave = tid >> 6, lane = tid & 63;
    const int row0 = blockIdx.x * 32;

    // ---- aggregation phase ----
    {
        const int p = lane >> 4;   // edge slot 0..3
        const int q = lane & 15;   // 16B chunk
        for (int i = 0; i < 8; ++i) {
            const int ln = wave * 8 + i;
            const int node = row0 + ln;
            int s0 = 0, s1 = 0;
            if (node < N_NODES) { s0 = row_ptr[node]; s1 = row_ptr[node + 1]; }
            float a[8] = {};
            int j = s0;
            for (; j + 16 <= s1; j += 16) {  // 4 gathers in flight (covers deg 16)
                int ea = esrc[j + p], eb = esrc[j + p + 4];
                int ec = esrc[j + p + 8], ed = esrc[j + p + 12];
                bf16x8 va = *(const bf16x8*)(hb + ((size_t)ea << 7) + (q << 3));
                bf16x8 vb = *(const bf16x8*)(hb + ((size_t)eb << 7) + (q << 3));
                bf16x8 vc = *(const bf16x8*)(hb + ((size_t)ec << 7) + (q << 3));
                bf16x8 vd = *(const bf16x8*)(hb + ((size_t)ed << 7) + (q << 3));
#pragma unroll
                for (int t = 0; t < 8; ++t)
                    a[t] += (bf2f((unsigned short)va[t]) + bf2f((unsigned short)vb[t])) +
                            (bf2f((unsigned short)vc[t]) + bf2f((unsigned short)vd[t]));
            }
            for (; j + 8 <= s1; j += 8) {
                int ea = esrc[j + p], eb = esrc[j + p + 4];
                bf16x8 va = *(const bf16x8*)(hb + ((size_t)ea << 7) + (q << 3));
                bf16x8 vb = *(const bf16x8*)(hb + ((size_t)eb << 7) + (q << 3));
#pragma unroll
                for (int t = 0; t < 8; ++t)
                    a[t] += bf2f((unsigned short)va[t]) + bf2f((unsigned short)vb[t]);
            }
            if (j + p < s1) {
                bf16x8 v = *(const bf16x8*)(hb + ((size_t)esrc[j + p] << 7) + (q << 3));
#pragma unroll
                for (int t = 0; t < 8; ++t) a[t] += bf2f((unsigned short)v[t]);
            }
            if (j + p + 4 < s1) {
                bf16x8 v = *(const bf16x8*)(hb + ((size_t)esrc[j + p + 4] << 7) + (q << 3));
#pragma unroll
                for (int t = 0; t < 8; ++t) a[t] += bf2f((unsigned short)v[t]);
            }
#pragma unroll
            for (int t = 0; t < 8; ++t) {
                a[t] += __shfl_xor(a[t], 16, 64);
                a[t] += __shfl_xor(a[t], 32, 64);
            }
            if (p == 0) {
                float dinv = 1.0f / (float)max(s1 - s0, 1);
                bf16x8 o;
#pragma unroll
                for (int t = 0; t < 8; ++t) o[t] = (short)f2bf(a[t] * dinv);
                int c16 = q ^ (ln & 7);  // swizzle
                *(bf16x8*)(sAgg + ln * 128 + (c16 << 3)) = o;
            }
        }
    }
    __syncthreads();

    // ---- dual GEMM phase: wave -> (row-tile rt, col-half ch) ----
    const int g = lane >> 4, r = lane & 15;
    const int rt = wave & 1, ch = wave >> 1;
    const int row_base = row0 + rt * 16;
    const int srow = min(row_base + r, N_NODES - 1);
    bf16x8 sv[4];  // prefetch self rows
#pragma unroll
    for (int kb = 0; kb < 4; ++kb)
        sv[kb] = *(const bf16x8*)(hb + (size_t)srow * H_F + kb * 32 + g * 8);
    f32x4 acc[4] = {};
#pragma unroll
    for (int kb = 0; kb < 8; ++kb) {
        bf16x8 afr;
        if (kb < 4) {  // agg operand from LDS (swizzled)
            int c16 = (kb * 4 + g) ^ (r & 7);
            afr = *(const bf16x8*)(sAgg + (rt * 16 + r) * 128 + (c16 << 3));
        } else {
            afr = sv[kb - 4];
        }
#pragma unroll
        for (int ct = 0; ct < 4; ++ct) {
            int col = ch * 64 + ct * 16 + r;
            bf16x8 bfr = *(const bf16x8*)(Bp + ((size_t)(kb * 4 + g) * H_F + col) * 8);
            acc[ct] = __builtin_amdgcn_mfma_f32_16x16x32_bf16(afr, bfr, acc[ct], 0, 0, 0);
        }
    }
#pragma unroll
    for (int ct = 0; ct < 4; ++ct) {
        int col = ch * 64 + ct * 16 + r;
        float bv = bias[col];
#pragma unroll
        for (int i = 0; i < 4; ++i) {
            int row = row_base + g * 4 + i;
            if (row < N_NODES)
                hbout[(size_t)row * H_F + col] = f2bf(fmaxf(acc[ct][i] + bv, 0.f));
        }
    }
}

// ================= lin1 (64-row blocks): out = hb @ W + b, fp32 =================
__global__ __launch_bounds__(256, 4) void lin1_mfma(
        const unsigned short* __restrict__ hb, const unsigned short* __restrict__ Bp,
        const float* __restrict__ bias, float* __restrict__ out) {
    const int tid = threadIdx.x;
    const int wave = tid >> 6, lane = tid & 63;
    const int g = lane >> 4, r = lane & 15;
    const int row_base = blockIdx.x * 64 + wave * 16;
    const int row = min(row_base + r, N_NODES - 1);
    bf16x8 av[4];
#pragma unroll
    for (int kb = 0; kb < 4; ++kb)
        av[kb] = *(const bf16x8*)(hb + (size_t)row * H_F + kb * 32 + g * 8);
    f32x4 acc[4] = {};
#pragma unroll
    for (int kb = 0; kb < 4; ++kb) {
#pragma unroll
        for (int ct = 0; ct < 4; ++ct) {
            bf16x8 bfr = *(const bf16x8*)(Bp + ((size_t)(kb * 4 + g) * OUT_F + ct * 16 + r) * 8);
            acc[ct] = __builtin_amdgcn_mfma_f32_16x16x32_bf16(av[kb], bfr, acc[ct], 0, 0, 0);
        }
    }
#pragma unroll
    for (int ct = 0; ct < 4; ++ct) {
        int col = ct * 16 + r;
        float bv = bias[col];
#pragma unroll
        for (int i = 0; i < 4; ++i) {
            int orow = row_base + g * 4 + i;
            if (orow < N_NODES)
                out[(size_t)orow * OUT_F + col] = acc[ct][i] + bv;
        }
    }
}

extern "C" void kernel_launch(void* const* d_in, const int* in_sizes, int n_in,
                              void* d_out, int out_size, void* d_ws, size_t ws_size,
                              hipStream_t stream) {
    const float* x       = (const float*)d_in[0];
    const int*   ei      = (const int*)d_in[1];
    const float* lin0_w  = (const float*)d_in[2];
    const float* lin0_b  = (const float*)d_in[3];
    const float* conv_wl = (const float*)d_in[4];
    const float* conv_bl = (const float*)d_in[5];
    const float* conv_wr = (const float*)d_in[6];
    const float* lin1_w  = (const float*)d_in[7];
    const float* lin1_b  = (const float*)d_in[8];
    float* out = (float*)d_out;

    char* ws = (char*)d_ws;
    size_t off = 0;
    auto alloc = [&](size_t bytes) {
        void* p = ws + off;
        off = (off + bytes + 255) & ~(size_t)255;
        return p;
    };
    int* cnt     = (int*)alloc((size_t)N_NODES * 16 * 4);  // stride-16: 1 counter / 64B line
    int* row_ptr = (int*)alloc((size_t)(N_NODES + 1) * 4);
    int* esrc    = (int*)alloc((size_t)E_EDGES * 4);
    int* rank    = (int*)alloc((size_t)E_EDGES * 4);
    int* tmp     = (int*)alloc((size_t)NB_SCAN * 1024 * 4);
    int* bsum    = (int*)alloc(64 * 4);
    unsigned short* hb0  = (unsigned short*)alloc((size_t)NPAD * H_F * 2);
    unsigned short* hb1  = (unsigned short*)alloc((size_t)NPAD * H_F * 2);
    unsigned short* BpL0 = (unsigned short*)alloc((size_t)IN_F * H_F * 2);
    unsigned short* BpCv = (unsigned short*)alloc((size_t)L_LAYERS * 256 * H_F * 2);
    unsigned short* BpL1 = (unsigned short*)alloc((size_t)H_F * OUT_F * 2);

    // ---- prep ----
    hipMemsetAsync(cnt, 0, (size_t)N_NODES * 16 * 4, stream);
    prep_all<<<544, 256, 0, stream>>>(lin0_w, conv_wl, conv_wr, lin1_w, BpL0, BpCv, BpL1);

    // ---- count (first) + lin0 GEMM in one grid ----
    lin0_count<<<COUNT_BLOCKS + LIN0_BLOCKS, 256, 0, stream>>>(
        x, BpL0, lin0_b, hb0, ei, cnt, rank);

    // ---- scan + atomic-free place ----
    scanA_kernel<<<NB_SCAN, 1024, 0, stream>>>(cnt, tmp, bsum);
    scanB_kernel<<<1, 64, 0, stream>>>(bsum);
    scanC_kernel<<<NB_SCAN, 1024, 0, stream>>>(tmp, bsum, row_ptr);
    place2_kernel<<<COUNT_BLOCKS, 256, 0, stream>>>(ei, row_ptr, rank, esrc);

    // ---- 3 fused agg+conv layers (32-row blocks) ----
    unsigned short* h = hb0;
    unsigned short* nh = hb1;
    for (int l = 0; l < L_LAYERS; ++l) {
        conv_fused<<<NPAD / 32, 256, 0, stream>>>(h, row_ptr, esrc,
                                                  BpCv + (size_t)l * 256 * H_F,
                                                  conv_bl + (size_t)l * H_F, nh);
        unsigned short* t = h; h = nh; nh = t;
    }

    // ---- lin1 ----
    lin1_mfma<<<NPAD / 64, 256, 0, stream>>>(h, BpL1, lin1_b, out);
}

// Round 12
// 299.452 us; speedup vs baseline: 5.1997x; 1.0378x over previous
//
#include <hip/hip_runtime.h>
#include <hip/hip_bf16.h>

#define N_NODES 50000
#define E_EDGES 800000
#define IN_F 256
#define H_F 128
#define OUT_F 64
#define L_LAYERS 3
#define NB_SCAN 49    // ceil(50000/1024)
#define LIN0_BLOCKS 784    // 64-row blocks
#define E_STRIDE 200704    // 784*256
#define NPAD 50176         // 784*64 = 3136*16

typedef __attribute__((ext_vector_type(8))) short bf16x8;
typedef __attribute__((ext_vector_type(4))) float f32x4;

static __device__ __forceinline__ float bf2f(unsigned short u) {
    return __uint_as_float(((unsigned int)u) << 16);
}
static __device__ __forceinline__ unsigned short f2bf(float f) {
    unsigned int b = __float_as_uint(f);
    return (unsigned short)((b + 0x7FFFu + ((b >> 16) & 1u)) >> 16);  // RTN-even
}

// ================= scan (row_ptr from strided cnt) =================
__global__ __launch_bounds__(1024) void scanA_kernel(const int* __restrict__ cnt,
                                                     int* __restrict__ tmp,
                                                     int* __restrict__ bsum) {
    __shared__ int buf[1024];
    const int tid = threadIdx.x;
    const int i = blockIdx.x * 1024 + tid;
    int v = (i < N_NODES) ? cnt[(size_t)i << 4] : 0;   // stride-16
    buf[tid] = v;
    __syncthreads();
    for (int off = 1; off < 1024; off <<= 1) {
        int t = (tid >= off) ? buf[tid - off] : 0;
        __syncthreads();
        buf[tid] += t;
        __syncthreads();
    }
    tmp[i] = buf[tid];
    if (tid == 1023) bsum[blockIdx.x] = buf[1023];
}

__global__ void scanB_kernel(int* __restrict__ bsum) {
    int t = threadIdx.x;  // 64
    int v = (t < NB_SCAN) ? bsum[t] : 0;
    int incl = v;
    for (int off = 1; off < 64; off <<= 1) {
        int u = __shfl_up(incl, off, 64);
        if (t >= off) incl += u;
    }
    if (t < NB_SCAN) bsum[t] = incl - v;  // exclusive
}

__global__ __launch_bounds__(1024) void scanC_kernel(const int* __restrict__ tmp,
                                                     const int* __restrict__ bsum,
                                                     int* __restrict__ row_ptr) {
    const int i = blockIdx.x * 1024 + threadIdx.x;
    if (i < N_NODES) row_ptr[i + 1] = tmp[i] + bsum[i >> 10];
    if (i == 0) row_ptr[0] = 0;
}

// ================= atomic-free placement =================
__global__ void place2_kernel(const int* __restrict__ ei, const int* __restrict__ row_ptr,
                              const int* __restrict__ rank, int* __restrict__ esrc) {
    int e = blockIdx.x * blockDim.x + threadIdx.x;
    if (e < E_EDGES) {
        int s = ei[e];
        int d = ei[E_EDGES + e];
        esrc[row_ptr[d] + rank[e]] = s;
    }
}

// ================= merged weight prep =================
// Fragment layout: dst[(gg*C + c)*8 + j] = bf16(src[(gg*8+j)*C + c])
__global__ void prep_all(const float* __restrict__ lin0_w, const float* __restrict__ conv_wl,
                         const float* __restrict__ conv_wr, const float* __restrict__ lin1_w,
                         unsigned short* __restrict__ BpL0, unsigned short* __restrict__ BpCv,
                         unsigned short* __restrict__ BpL1) {
    int gid = blockIdx.x * 256 + threadIdx.x;
    if (gid < 32768) {  // lin0: K=256, C=128
        int idx = gid;
        int j = idx & 7, rest = idx >> 3;
        int c = rest & 127, gg = rest >> 7;
        BpL0[idx] = f2bf(lin0_w[(size_t)(gg * 8 + j) * 128 + c]);
    } else if (gid < 32768 + 3 * 32768) {  // conv dual: virtual B=[wl;wr], K=256, C=128
        int t = gid - 32768;
        int l = t >> 15, idx = t & 32767;
        int j = idx & 7, rest = idx >> 3;
        int c = rest & 127, gg = rest >> 7;
        int k = gg * 8 + j;
        const float* wl = conv_wl + (size_t)l * 16384;
        const float* wr = conv_wr + (size_t)l * 16384;
        float v = (k < 128) ? wl[(size_t)k * 128 + c] : wr[(size_t)(k - 128) * 128 + c];
        BpCv[t] = f2bf(v);
    } else if (gid < 32768 + 3 * 32768 + 8192) {  // lin1: K=128, C=64
        int idx = gid - (32768 + 3 * 32768);
        int j = idx & 7, rest = idx >> 3;
        int c = rest & 63, gg = rest >> 6;
        BpL1[idx] = f2bf(lin1_w[(size_t)(gg * 8 + j) * 64 + c]);
    }
}

// ================= lin0 GEMM with count atomics overlapped in-block =================
// Each of 784 blocks: issue 4 count atomics/thread, run 64-row GEMM, store ranks last.
// A-frag: row=lane&15, k=kb*32+(lane>>4)*8+j. D: col=lane&15, row=(lane>>4)*4+i.
__global__ __launch_bounds__(256, 4) void lin0_count(
        const float* __restrict__ x, const unsigned short* __restrict__ Bp,
        const float* __restrict__ bias, unsigned short* __restrict__ hb,
        const int* __restrict__ ei, int* __restrict__ cnt, int* __restrict__ rank) {
    const int tid = threadIdx.x;
    const int gtid = blockIdx.x * 256 + tid;

    // ---- issue count atomics (latency hidden under GEMM) ----
    int rk[4];
    bool val[4];
#pragma unroll
    for (int k = 0; k < 4; ++k) {
        int e = gtid + k * E_STRIDE;
        val[k] = (e < E_EDGES);
        if (val[k]) {
            int d = ei[E_EDGES + e];
            rk[k] = atomicAdd(&cnt[(size_t)d << 4], 1);  // 1 counter per 64B line
        }
    }

    // ---- 64-row GEMM ----
    const int wave = tid >> 6, lane = tid & 63;
    const int g = lane >> 4, r = lane & 15;
    const int row_base = blockIdx.x * 64 + wave * 16;
    const int row = min(row_base + r, N_NODES - 1);
    const float* xp = x + (size_t)row * IN_F + g * 8;
    f32x4 acc[8] = {};
#pragma unroll
    for (int kb = 0; kb < 8; ++kb) {
        float4 v0 = *(const float4*)(xp + kb * 32);
        float4 v1 = *(const float4*)(xp + kb * 32 + 4);
        bf16x8 afr;
        afr[0] = (short)f2bf(v0.x); afr[1] = (short)f2bf(v0.y);
        afr[2] = (short)f2bf(v0.z); afr[3] = (short)f2bf(v0.w);
        afr[4] = (short)f2bf(v1.x); afr[5] = (short)f2bf(v1.y);
        afr[6] = (short)f2bf(v1.z); afr[7] = (short)f2bf(v1.w);
#pragma unroll
        for (int ct = 0; ct < 8; ++ct) {
            bf16x8 bfr = *(const bf16x8*)(Bp + ((size_t)(kb * 4 + g) * H_F + ct * 16 + r) * 8);
            acc[ct] = __builtin_amdgcn_mfma_f32_16x16x32_bf16(afr, bfr, acc[ct], 0, 0, 0);
        }
    }
#pragma unroll
    for (int ct = 0; ct < 8; ++ct) {
        int col = ct * 16 + r;
        float bv = bias[col];
#pragma unroll
        for (int i = 0; i < 4; ++i) {
            int orow = row_base + g * 4 + i;
            if (orow < N_NODES)
                hb[(size_t)orow * H_F + col] = f2bf(fmaxf(acc[ct][i] + bv, 0.f));
        }
    }

    // ---- epilogue: store ranks (atomics have long since returned) ----
#pragma unroll
    for (int k = 0; k < 4; ++k)
        if (val[k]) rank[gtid + k * E_STRIDE] = rk[k];
}

// ================= fused SAGEConv: 16-row blocks (128 thr, 2 waves) =================
// Agg: wave w aggregates nodes w*8..w*8+7 into swizzled LDS.
// GEMM: wave w -> col-half w; 16 rows x 64 cols, K=256 (agg from LDS, self prefetched).
__global__ __launch_bounds__(128, 8) void conv_fused(
        const unsigned short* __restrict__ hb, const int* __restrict__ row_ptr,
        const int* __restrict__ esrc, const unsigned short* __restrict__ Bp,
        const float* __restrict__ bias, unsigned short* __restrict__ hbout) {
    __shared__ unsigned short sAgg[16 * 128];  // 4KB, XOR-swizzled 16B chunks
    const int tid = threadIdx.x;
    const int wave = tid >> 6, lane = tid & 63;
    const int row0 = blockIdx.x * 16;

    // ---- aggregation phase ----
    {
        const int p = lane >> 4;   // edge slot 0..3
        const int q = lane & 15;   // 16B chunk
        for (int i = 0; i < 8; ++i) {
            const int ln = wave * 8 + i;
            const int node = row0 + ln;
            int s0 = 0, s1 = 0;
            if (node < N_NODES) { s0 = row_ptr[node]; s1 = row_ptr[node + 1]; }
            float a[8] = {};
            int j = s0;
            for (; j + 16 <= s1; j += 16) {  // 4 gathers in flight (covers deg 16)
                int ea = esrc[j + p], eb = esrc[j + p + 4];
                int ec = esrc[j + p + 8], ed = esrc[j + p + 12];
                bf16x8 va = *(const bf16x8*)(hb + ((size_t)ea << 7) + (q << 3));
                bf16x8 vb = *(const bf16x8*)(hb + ((size_t)eb << 7) + (q << 3));
                bf16x8 vc = *(const bf16x8*)(hb + ((size_t)ec << 7) + (q << 3));
                bf16x8 vd = *(const bf16x8*)(hb + ((size_t)ed << 7) + (q << 3));
#pragma unroll
                for (int t = 0; t < 8; ++t)
                    a[t] += (bf2f((unsigned short)va[t]) + bf2f((unsigned short)vb[t])) +
                            (bf2f((unsigned short)vc[t]) + bf2f((unsigned short)vd[t]));
            }
            for (; j + 8 <= s1; j += 8) {
                int ea = esrc[j + p], eb = esrc[j + p + 4];
                bf16x8 va = *(const bf16x8*)(hb + ((size_t)ea << 7) + (q << 3));
                bf16x8 vb = *(const bf16x8*)(hb + ((size_t)eb << 7) + (q << 3));
#pragma unroll
                for (int t = 0; t < 8; ++t)
                    a[t] += bf2f((unsigned short)va[t]) + bf2f((unsigned short)vb[t]);
            }
            if (j + p < s1) {
                bf16x8 v = *(const bf16x8*)(hb + ((size_t)esrc[j + p] << 7) + (q << 3));
#pragma unroll
                for (int t = 0; t < 8; ++t) a[t] += bf2f((unsigned short)v[t]);
            }
            if (j + p + 4 < s1) {
                bf16x8 v = *(const bf16x8*)(hb + ((size_t)esrc[j + p + 4] << 7) + (q << 3));
#pragma unroll
                for (int t = 0; t < 8; ++t) a[t] += bf2f((unsigned short)v[t]);
            }
#pragma unroll
            for (int t = 0; t < 8; ++t) {
                a[t] += __shfl_xor(a[t], 16, 64);
                a[t] += __shfl_xor(a[t], 32, 64);
            }
            if (p == 0) {
                float dinv = 1.0f / (float)max(s1 - s0, 1);
                bf16x8 o;
#pragma unroll
                for (int t = 0; t < 8; ++t) o[t] = (short)f2bf(a[t] * dinv);
                int c16 = q ^ (ln & 7);  // swizzle
                *(bf16x8*)(sAgg + ln * 128 + (c16 << 3)) = o;
            }
        }
    }
    __syncthreads();

    // ---- dual GEMM phase: wave w -> col-half w ----
    const int g = lane >> 4, r = lane & 15;
    const int ch = wave;
    const int srow = min(row0 + r, N_NODES - 1);
    bf16x8 sv[4];  // prefetch self rows
#pragma unroll
    for (int kb = 0; kb < 4; ++kb)
        sv[kb] = *(const bf16x8*)(hb + (size_t)srow * H_F + kb * 32 + g * 8);
    f32x4 acc[4] = {};
#pragma unroll
    for (int kb = 0; kb < 8; ++kb) {
        bf16x8 afr;
        if (kb < 4) {  // agg operand from LDS (swizzled)
            int c16 = (kb * 4 + g) ^ (r & 7);
            afr = *(const bf16x8*)(sAgg + r * 128 + (c16 << 3));
        } else {
            afr = sv[kb - 4];
        }
#pragma unroll
        for (int ct = 0; ct < 4; ++ct) {
            int col = ch * 64 + ct * 16 + r;
            bf16x8 bfr = *(const bf16x8*)(Bp + ((size_t)(kb * 4 + g) * H_F + col) * 8);
            acc[ct] = __builtin_amdgcn_mfma_f32_16x16x32_bf16(afr, bfr, acc[ct], 0, 0, 0);
        }
    }
#pragma unroll
    for (int ct = 0; ct < 4; ++ct) {
        int col = ch * 64 + ct * 16 + r;
        float bv = bias[col];
#pragma unroll
        for (int i = 0; i < 4; ++i) {
            int row = row0 + g * 4 + i;
            if (row < N_NODES)
                hbout[(size_t)row * H_F + col] = f2bf(fmaxf(acc[ct][i] + bv, 0.f));
        }
    }
}

// ================= lin1 (64-row blocks): out = hb @ W + b, fp32 =================
__global__ __launch_bounds__(256, 4) void lin1_mfma(
        const unsigned short* __restrict__ hb, const unsigned short* __restrict__ Bp,
        const float* __restrict__ bias, float* __restrict__ out) {
    const int tid = threadIdx.x;
    const int wave = tid >> 6, lane = tid & 63;
    const int g = lane >> 4, r = lane & 15;
    const int row_base = blockIdx.x * 64 + wave * 16;
    const int row = min(row_base + r, N_NODES - 1);
    bf16x8 av[4];
#pragma unroll
    for (int kb = 0; kb < 4; ++kb)
        av[kb] = *(const bf16x8*)(hb + (size_t)row * H_F + kb * 32 + g * 8);
    f32x4 acc[4] = {};
#pragma unroll
    for (int kb = 0; kb < 4; ++kb) {
#pragma unroll
        for (int ct = 0; ct < 4; ++ct) {
            bf16x8 bfr = *(const bf16x8*)(Bp + ((size_t)(kb * 4 + g) * OUT_F + ct * 16 + r) * 8);
            acc[ct] = __builtin_amdgcn_mfma_f32_16x16x32_bf16(av[kb], bfr, acc[ct], 0, 0, 0);
        }
    }
#pragma unroll
    for (int ct = 0; ct < 4; ++ct) {
        int col = ct * 16 + r;
        float bv = bias[col];
#pragma unroll
        for (int i = 0; i < 4; ++i) {
            int orow = row_base + g * 4 + i;
            if (orow < N_NODES)
                out[(size_t)orow * OUT_F + col] = acc[ct][i] + bv;
        }
    }
}

extern "C" void kernel_launch(void* const* d_in, const int* in_sizes, int n_in,
                              void* d_out, int out_size, void* d_ws, size_t ws_size,
                              hipStream_t stream) {
    const float* x       = (const float*)d_in[0];
    const int*   ei      = (const int*)d_in[1];
    const float* lin0_w  = (const float*)d_in[2];
    const float* lin0_b  = (const float*)d_in[3];
    const float* conv_wl = (const float*)d_in[4];
    const float* conv_bl = (const float*)d_in[5];
    const float* conv_wr = (const float*)d_in[6];
    const float* lin1_w  = (const float*)d_in[7];
    const float* lin1_b  = (const float*)d_in[8];
    float* out = (float*)d_out;

    char* ws = (char*)d_ws;
    size_t off = 0;
    auto alloc = [&](size_t bytes) {
        void* p = ws + off;
        off = (off + bytes + 255) & ~(size_t)255;
        return p;
    };
    int* cnt     = (int*)alloc((size_t)N_NODES * 16 * 4);  // stride-16: 1 counter / 64B line
    int* row_ptr = (int*)alloc((size_t)(N_NODES + 1) * 4);
    int* esrc    = (int*)alloc((size_t)E_EDGES * 4);
    int* rank    = (int*)alloc((size_t)E_EDGES * 4);
    int* tmp     = (int*)alloc((size_t)NB_SCAN * 1024 * 4);
    int* bsum    = (int*)alloc(64 * 4);
    unsigned short* hb0  = (unsigned short*)alloc((size_t)NPAD * H_F * 2);
    unsigned short* hb1  = (unsigned short*)alloc((size_t)NPAD * H_F * 2);
    unsigned short* BpL0 = (unsigned short*)alloc((size_t)IN_F * H_F * 2);
    unsigned short* BpCv = (unsigned short*)alloc((size_t)L_LAYERS * 256 * H_F * 2);
    unsigned short* BpL1 = (unsigned short*)alloc((size_t)H_F * OUT_F * 2);

    // ---- prep ----
    hipMemsetAsync(cnt, 0, (size_t)N_NODES * 16 * 4, stream);
    prep_all<<<544, 256, 0, stream>>>(lin0_w, conv_wl, conv_wr, lin1_w, BpL0, BpCv, BpL1);

    // ---- lin0 GEMM with in-block overlapped count atomics ----
    lin0_count<<<LIN0_BLOCKS, 256, 0, stream>>>(x, BpL0, lin0_b, hb0, ei, cnt, rank);

    // ---- scan + atomic-free place ----
    scanA_kernel<<<NB_SCAN, 1024, 0, stream>>>(cnt, tmp, bsum);
    scanB_kernel<<<1, 64, 0, stream>>>(bsum);
    scanC_kernel<<<NB_SCAN, 1024, 0, stream>>>(tmp, bsum, row_ptr);
    place2_kernel<<<(E_EDGES + 255) / 256, 256, 0, stream>>>(ei, row_ptr, rank, esrc);

    // ---- 3 fused agg+conv layers (16-row blocks, 128 thr) ----
    unsigned short* h = hb0;
    unsigned short* nh = hb1;
    for (int l = 0; l < L_LAYERS; ++l) {
        conv_fused<<<NPAD / 16, 128, 0, stream>>>(h, row_ptr, esrc,
                                                  BpCv + (size_t)l * 256 * H_F,
                                                  conv_bl + (size_t)l * H_F, nh);
        unsigned short* t = h; h = nh; nh = t;
    }

    // ---- lin1 ----
    lin1_mfma<<<NPAD / 64, 256, 0, stream>>>(h, BpL1, lin1_b, out);
}